// Round 6
// baseline (2612.678 us; speedup 1.0000x reference)
//
#include <hip/hip_runtime.h>

typedef __bf16 bf16;
typedef __bf16 bf16x4 __attribute__((ext_vector_type(4)));
typedef __bf16 bf16x8 __attribute__((ext_vector_type(8)));
typedef float  f32x4  __attribute__((ext_vector_type(4)));

// B=64, S=512, OBS=128, D=512, H=8, F=2048, L=4, A=16; rows M = B*513 = 32832
// R21: all GEMMs -> gemm256, a 256x256xBK64 8-wave counted-vmcnt template
// (T3+T4 port).  Per K-tile two phases (ks=0/1), each:
//   vmcnt(4); s_barrier; [stage next-tile region: 4x global_load_lds];
//   12x ds_read_b128; 32x MFMA
// vmcnt never drains in steady state (waited loads were issued 2-4 phases
// earlier); vmcnt(0) only at the last tile.  LDS 128KB (A,B x dbuf x 2 ks x
// [256][32] linear), 1 block/CU -- latency hiding is intra-block (the
// R16/R19/R20 experiments confirmed dbuf-pipelining at 128^2 only trades away
// occupancy).  Epilogue operand-swapped + bf16x4 (R18-verified).  XCD swizzle,
// fused QKV, strided qkv, FFN chunking unchanged.

__device__ __forceinline__ void cp16(const bf16* g, bf16* l)
{
    __builtin_amdgcn_global_load_lds(
        (const __attribute__((address_space(1))) void*)g,
        (__attribute__((address_space(3))) void*)l,
        16, 0, 0);
}

__global__ __launch_bounds__(256) void cvt_bf16(
    const float* __restrict__ src, bf16* __restrict__ dst, int n)
{
    for (int i = blockIdx.x * 256 + threadIdx.x; i < n; i += gridDim.x * 256)
        dst[i] = (bf16)src[i];
}

__global__ __launch_bounds__(256) void transpose_f32(
    const float* __restrict__ W, bf16* __restrict__ WT, int K, int N, long elemOff)
{
    __shared__ bf16 tile[32][33];
    const int bn = blockIdx.x * 32;
    const int bk = blockIdx.y * 32;
    const int tx = threadIdx.x & 31, ty = threadIdx.x >> 5;
    for (int r = 0; r < 32; r += 8)
        tile[ty + r][tx] = (bf16)W[elemOff + (long)(bk + ty + r) * N + (bn + tx)];
    __syncthreads();
    for (int r = 0; r < 32; r += 8)
        WT[(long)(bn + ty + r) * K + (bk + tx)] = tile[tx][ty + r];
}

__global__ __launch_bounds__(256) void build_x0(
    const float* __restrict__ hs, const int* __restrict__ resets,
    bf16* __restrict__ xb)
{
    const int b = blockIdx.x;
    const bool rz = (resets[b] != 0);
    const long base = (long)b * 513 * 512;
    for (int d = threadIdx.x; d < 512; d += 256)
        xb[base + d] = rz ? (bf16)0.f : (bf16)hs[b * 512 + d];
}

__global__ __launch_bounds__(256) void concat3(
    const float* __restrict__ a, const float* __restrict__ b,
    const float* __restrict__ c, float* __restrict__ d)
{
    const int i = blockIdx.x * 256 + threadIdx.x;
    if (i < 512)       d[i] = a[i];
    else if (i < 1024) d[i] = b[i - 512];
    else if (i < 1536) d[i] = c[i - 1024];
}

// GEMM: C[M,N] = A[M,K] @ BT[N,K]^T + bias(fp32).  256x256 tile, BK=64,
// 512 threads = 8 waves (wr=w>>2 M-half, wc=w&3 N-quarter), per-wave 128x64.
// Counted-vmcnt 2-phase-per-K-tile schedule (see file header).  LDS linear
// [dbuf][ks][256][32] per operand (128KB).  K%64==0, N%256==0, M>=256; M tail
// via overlap clamp.  A row stride lda, C row stride ldc.  Bijective XCD
// swizzle (m204).  ROWMAP==1: row += row/512 + 1.
// ACT: 0=none 1=relu 2=relu+eps 3=relu+eps iff col<1024.
template<int ROWMAP, int ACT>
__global__ __launch_bounds__(512) void gemm256(
    const bf16* __restrict__ A, const bf16* __restrict__ BT,
    const float* __restrict__ bias, bf16* __restrict__ outB,
    int M, int N, int K, int lda, int ldc)
{
    __shared__ bf16 As[2][2][8192];   // [dbuf][ks][row*32 + k]
    __shared__ bf16 Bs[2][2][8192];
    const int tid  = threadIdx.x;
    const int w    = tid >> 6;
    const int lane = tid & 63;
    const int q    = lane >> 4;
    const int lm   = lane & 15;
    const int wr   = w >> 2;          // M-half
    const int wc   = w & 3;           // N-quarter

    // bijective XCD swizzle (m204)
    int flat;
    {
        const int nwg  = gridDim.x * gridDim.y;
        const int orig = blockIdx.y * gridDim.x + blockIdx.x;
        const int qq = nwg >> 3, rr = nwg & 7;
        const int xcd = orig & 7, idx = orig >> 3;
        flat = (xcd < rr ? xcd * (qq + 1) : rr * (qq + 1) + (xcd - rr) * qq) + idx;
    }
    const int bx = flat % gridDim.x;
    const int by = flat / gridDim.x;
    int m0 = by * 256;
    if (m0 > M - 256) m0 = M - 256;   // tail overlap clamp
    const int n0 = bx * 256;

    // staging geometry: region = [256 rows][32 k] (16KB).  Wave w issue i
    // covers rows w*32+i*16+(lane>>2), k-seg (lane&3)*8; DMA writes linearly
    // at region_base + w*1024 + i*512 elems (wave-uniform base + lane*16B).
    const int srow = lane >> 2;
    const int scol = (lane & 3) * 8;
    const bf16* Ag = A  + (long)(m0 + w * 32 + srow) * lda + scol;
    const bf16* Bg = BT + (long)(n0 + w * 32 + srow) * K   + scol;
    const long lda16 = (long)lda * 16;
    const long K16   = (long)K * 16;
    bf16* AsF = &As[0][0][0];
    bf16* BsF = &Bs[0][0][0];
    const int sdst = w * 1024;
    const int aoff = (wr * 128 + lm) * 32 + q * 8;
    const int boff = (wc * 64  + lm) * 32 + q * 8;

    f32x4 acc[8][4];
    #pragma unroll
    for (int mi = 0; mi < 8; mi++)
        #pragma unroll
        for (int nj = 0; nj < 4; nj++)
            #pragma unroll
            for (int r = 0; r < 4; r++) acc[mi][nj][r] = 0.f;

    const int NT = K >> 6;

    // prologue: tile 0, both ks regions into buf 0 (8 loads/wave)
    #pragma unroll
    for (int ks = 0; ks < 2; ks++) {
        cp16(Ag + ks * 32,         AsF + ks * 8192 + sdst);
        cp16(Ag + lda16 + ks * 32, AsF + ks * 8192 + sdst + 512);
        cp16(Bg + ks * 32,         BsF + ks * 8192 + sdst);
        cp16(Bg + K16 + ks * 32,   BsF + ks * 8192 + sdst + 512);
    }

    for (int t = 0; t < NT; ++t) {
        const int  p  = t & 1;
        const long kn = (long)(t + 1) * 64;
        const bool st = (t + 1 < NT);

        // ---------------- phase ks = 0 ----------------
        // queue: [A0(t),B0(t) | A1(t),B1(t)] = 8 -> wait oldest 4 (this tile's ks0)
        asm volatile("s_waitcnt vmcnt(4)" ::: "memory");
        __builtin_amdgcn_s_barrier();
        asm volatile("" ::: "memory");
        {
            if (st) {                                  // stage (t+1, ks0) -> buf p^1
                const int rb = ((p ^ 1) * 2 + 0) * 8192 + sdst;
                cp16(Ag + kn,         AsF + rb);
                cp16(Ag + lda16 + kn, AsF + rb + 512);
                cp16(Bg + kn,         BsF + rb);
                cp16(Bg + K16 + kn,   BsF + rb + 512);
            }
            const bf16* Ap = AsF + (p * 2 + 0) * 8192 + aoff;
            const bf16* Bp = BsF + (p * 2 + 0) * 8192 + boff;
            bf16x8 af[8], bfr[4];
            #pragma unroll
            for (int mi = 0; mi < 8; mi++) af[mi]  = *(const bf16x8*)(Ap + mi * 512);
            #pragma unroll
            for (int nj = 0; nj < 4; nj++) bfr[nj] = *(const bf16x8*)(Bp + nj * 512);
            #pragma unroll
            for (int mi = 0; mi < 8; mi++)
                #pragma unroll
                for (int nj = 0; nj < 4; nj++)
                    acc[mi][nj] = __builtin_amdgcn_mfma_f32_16x16x32_bf16(
                        bfr[nj], af[mi], acc[mi][nj], 0, 0, 0);  // swapped
        }
        // ---------------- phase ks = 1 ----------------
        // queue: [A1(t),B1(t) | A0(t+1),B0(t+1)] -> wait oldest 4 (this tile's ks1)
        if (st) asm volatile("s_waitcnt vmcnt(4)" ::: "memory");
        else    asm volatile("s_waitcnt vmcnt(0)" ::: "memory");  // tail drain
        __builtin_amdgcn_s_barrier();
        asm volatile("" ::: "memory");
        {
            if (st) {                                  // stage (t+1, ks1) -> buf p^1
                const int rb = ((p ^ 1) * 2 + 1) * 8192 + sdst;
                cp16(Ag + kn + 32,         AsF + rb);
                cp16(Ag + lda16 + kn + 32, AsF + rb + 512);
                cp16(Bg + kn + 32,         BsF + rb);
                cp16(Bg + K16 + kn + 32,   BsF + rb + 512);
            }
            const bf16* Ap = AsF + (p * 2 + 1) * 8192 + aoff;
            const bf16* Bp = BsF + (p * 2 + 1) * 8192 + boff;
            bf16x8 af[8], bfr[4];
            #pragma unroll
            for (int mi = 0; mi < 8; mi++) af[mi]  = *(const bf16x8*)(Ap + mi * 512);
            #pragma unroll
            for (int nj = 0; nj < 4; nj++) bfr[nj] = *(const bf16x8*)(Bp + nj * 512);
            #pragma unroll
            for (int mi = 0; mi < 8; mi++)
                #pragma unroll
                for (int nj = 0; nj < 4; nj++)
                    acc[mi][nj] = __builtin_amdgcn_mfma_f32_16x16x32_bf16(
                        bfr[nj], af[mi], acc[mi][nj], 0, 0, 0);
        }
    }

    // Swapped D layout: D-col (lane&15) = m, D-row (q*4+r) = n  [R18-verified]
    #pragma unroll
    for (int mi = 0; mi < 8; mi++) {
        int row = m0 + wr * 128 + mi * 16 + lm;
        if (ROWMAP == 1) row = row + (row >> 9) + 1;
        bf16* rowp = outB + (long)row * ldc;
        #pragma unroll
        for (int nj = 0; nj < 4; nj++) {
            const int colb = n0 + wc * 64 + nj * 16 + q * 4;
            const f32x4 bv4 = *(const f32x4*)(bias + colb);
            bf16x4 o;
            #pragma unroll
            for (int r = 0; r < 4; r++) {
                float vv = acc[mi][nj][r] + bv4[r];
                if (ACT == 1) vv = fmaxf(vv, 0.f);
                if (ACT == 2) vv = fmaxf(vv, 0.f) + 1e-3f;
                if (ACT == 3 && colb < 1024) vv = fmaxf(vv, 0.f) + 1e-3f;
                o[r] = (bf16)vv;
            }
            *(bf16x4*)(rowp + colb) = o;
        }
    }
}

// FAVOR+ attention, full MFMA.  Reads pq/pk/vv as column slices {0,512,1024}
// of the strided qkv[row][1536] buffer; writes ao back into the pq slice
// (per-(b,h) alias safe: each t8 tile's pq rows are staged before overwrite).
#define FP 72
__global__ __launch_bounds__(256) void favor_mfma(bf16* qkv)
{
    const int bh = blockIdx.x;
    const int b = bh >> 3, h = bh & 7;
    const long rbQ = (long)b * 513 * 1536 + h * 64;
    const long rbK = rbQ + 512;
    const long rbV = rbQ + 1024;

    __shared__ bf16 pkT[64][FP];
    __shared__ bf16 vT [64][FP];
    __shared__ bf16 kvT[64][FP];
    __shared__ bf16 pqS[64][FP];
    __shared__ float ksumS[64];
    __shared__ float denS[64];

    const int tid  = threadIdx.x;
    const int wave = tid >> 6;
    const int lane = tid & 63;
    const int q    = lane >> 4;
    const int lm   = lane & 15;
    const int wr   = wave >> 1, wc = wave & 1;
    const int mp   = (tid & 31) * 2;
    const int sr   = tid >> 5;

    if (tid < 64) ksumS[tid] = 0.f;
    float ksp0 = 0.f, ksp1 = 0.f;

    f32x4 akv[2][2];
    for (int i = 0; i < 2; i++) for (int j = 0; j < 2; j++)
        for (int r = 0; r < 4; r++) akv[i][j][r] = 0.f;

    for (int t8 = 0; t8 < 9; t8++) {
        const int s0 = t8 * 64;
        #pragma unroll
        for (int i = 0; i < 8; i++) {
            const int s  = sr + i * 8;
            const int gs = s0 + s;
            unsigned pkw = 0, vw = 0;
            if (gs < 513) {
                pkw = *(const unsigned*)(qkv + rbK + (long)gs * 1536 + mp);
                vw  = *(const unsigned*)(qkv + rbV + (long)gs * 1536 + mp);
            }
            union { unsigned u; bf16 hh[2]; } pu, vu;
            pu.u = pkw; vu.u = vw;
            pkT[mp][s]     = pu.hh[0];
            pkT[mp + 1][s] = pu.hh[1];
            vT[mp][s]      = vu.hh[0];
            vT[mp + 1][s]  = vu.hh[1];
            ksp0 += (float)pu.hh[0];
            ksp1 += (float)pu.hh[1];
        }
        __syncthreads();
        #pragma unroll
        for (int ks = 0; ks < 2; ks++) {
            bf16x8 a0 = *(const bf16x8*)(&pkT[wr * 32 + lm     ][ks * 32 + q * 8]);
            bf16x8 a1 = *(const bf16x8*)(&pkT[wr * 32 + 16 + lm][ks * 32 + q * 8]);
            bf16x8 b0 = *(const bf16x8*)(&vT [wc * 32 + lm     ][ks * 32 + q * 8]);
            bf16x8 b1 = *(const bf16x8*)(&vT [wc * 32 + 16 + lm][ks * 32 + q * 8]);
            akv[0][0] = __builtin_amdgcn_mfma_f32_16x16x32_bf16(a0, b0, akv[0][0], 0, 0, 0);
            akv[0][1] = __builtin_amdgcn_mfma_f32_16x16x32_bf16(a0, b1, akv[0][1], 0, 0, 0);
            akv[1][0] = __builtin_amdgcn_mfma_f32_16x16x32_bf16(a1, b0, akv[1][0], 0, 0, 0);
            akv[1][1] = __builtin_amdgcn_mfma_f32_16x16x32_bf16(a1, b1, akv[1][1], 0, 0, 0);
        }
        __syncthreads();
    }
    atomicAdd(&ksumS[mp],     ksp0);
    atomicAdd(&ksumS[mp + 1], ksp1);
    #pragma unroll
    for (int i = 0; i < 2; i++)
        #pragma unroll
        for (int j = 0; j < 2; j++)
            #pragma unroll
            for (int r = 0; r < 4; r++)
                kvT[wc * 32 + j * 16 + lm][wr * 32 + i * 16 + q * 4 + r] =
                    (bf16)akv[i][j][r];
    __syncthreads();

    const int prow = tid >> 2;
    const int pseg = (tid & 3) * 16;
    for (int t8 = 0; t8 < 9; t8++) {
        const int s0 = t8 * 64;
        const int gs = s0 + prow;
        if (gs < 513) {
            *(bf16x8*)(&pqS[prow][pseg])     = *(const bf16x8*)(qkv + rbQ + (long)gs * 1536 + pseg);
            *(bf16x8*)(&pqS[prow][pseg + 8]) = *(const bf16x8*)(qkv + rbQ + (long)gs * 1536 + pseg + 8);
        } else {
            bf16x8 z;
            for (int r = 0; r < 8; r++) z[r] = (bf16)0.f;
            *(bf16x8*)(&pqS[prow][pseg])     = z;
            *(bf16x8*)(&pqS[prow][pseg + 8]) = z;
        }
        __syncthreads();
        {
            const int s = tid >> 2, mb = (tid & 3) * 16;
            float dp = 0.f;
            #pragma unroll
            for (int m2 = 0; m2 < 16; m2++)
                dp += (float)pqS[s][mb + m2] * ksumS[mb + m2];
            dp += __shfl_xor(dp, 1);
            dp += __shfl_xor(dp, 2);
            if ((tid & 3) == 0) denS[s] = dp;
        }
        __syncthreads();
        f32x4 an[4];
        for (int j = 0; j < 4; j++)
            for (int r = 0; r < 4; r++) an[j][r] = 0.f;
        #pragma unroll
        for (int ks = 0; ks < 2; ks++) {
            bf16x8 a = *(const bf16x8*)(&pqS[wave * 16 + lm][ks * 32 + q * 8]);
            #pragma unroll
            for (int j = 0; j < 4; j++) {
                bf16x8 bb = *(const bf16x8*)(&kvT[j * 16 + lm][ks * 32 + q * 8]);
                an[j] = __builtin_amdgcn_mfma_f32_16x16x32_bf16(a, bb, an[j], 0, 0, 0);
            }
        }
        #pragma unroll
        for (int j = 0; j < 4; j++) {
            #pragma unroll
            for (int r = 0; r < 4; r++) {
                const int sl  = wave * 16 + q * 4 + r;
                const int gs2 = s0 + sl;
                if (gs2 < 513) {
                    const int d = j * 16 + lm;
                    qkv[rbQ + (long)gs2 * 1536 + d] = (bf16)(an[j][r] / denS[sl]);
                }
            }
        }
        __syncthreads();
    }
}

__global__ __launch_bounds__(256) void ln_res(
    const bf16* __restrict__ y, int ldy, const float* __restrict__ sc,
    const float* __restrict__ bi, bf16* __restrict__ xb)
{
    const int row  = blockIdx.x * 4 + (threadIdx.x >> 6);
    const int lane = threadIdx.x & 63;
    const bf16* yr = y  + (long)row * ldy + lane * 8;
    bf16*       xr = xb + (long)row * 512 + lane * 8;
    bf16x8 yv = *(const bf16x8*)yr;
    bf16x8 xv = *(const bf16x8*)xr;
    float v[8];
    float sum = 0.f;
    #pragma unroll
    for (int i = 0; i < 8; i++) { v[i] = (float)yv[i] + (float)xv[i]; sum += v[i]; }
    #pragma unroll
    for (int o = 32; o; o >>= 1) sum += __shfl_xor(sum, o);
    const float mean = sum * (1.f / 512.f);
    float vs = 0.f;
    #pragma unroll
    for (int i = 0; i < 8; i++) { float dd = v[i] - mean; vs += dd * dd; }
    #pragma unroll
    for (int o = 32; o; o >>= 1) vs += __shfl_xor(vs, o);
    const float rstd = rsqrtf(vs * (1.f / 512.f) + 1e-6f);
    bf16x8 ov;
    #pragma unroll
    for (int i = 0; i < 8; i++)
        ov[i] = (bf16)((v[i] - mean) * rstd * sc[lane * 8 + i] + bi[lane * 8 + i]);
    *(bf16x8*)xr = ov;
}

__global__ __launch_bounds__(256) void final_head(
    const bf16* __restrict__ xb, const float* __restrict__ Wqp,
    const float* __restrict__ bqp, float* __restrict__ out)
{
    const int b = blockIdx.x;
    const bf16* xr = xb + (long)b * 513 * 512;
    for (int i = threadIdx.x; i < 512; i += 256) out[b * 512 + i] = (float)xr[i];
    const int a = threadIdx.x & 15, g = threadIdx.x >> 4;
    float p = 0.f;
    for (int k = g * 32; k < g * 32 + 32; k++)
        p += (float)xr[k] * Wqp[k * 16 + a];
    __shared__ float red[256];
    red[threadIdx.x] = p;
    __syncthreads();
    if (threadIdx.x < 16) {
        float s = bqp[a];
        for (int g2 = 0; g2 < 16; g2++) s += red[g2 * 16 + a];
        out[64 * 512 + b * 16 + a] = s;
    }
}

extern "C" void kernel_launch(void* const* d_in, const int* in_sizes, int n_in,
                              void* d_out, int out_size, void* d_ws, size_t ws_size,
                              hipStream_t stream)
{
    (void)in_sizes; (void)n_in; (void)out_size; (void)ws_size;
    const float* hs    = (const float*)d_in[0];
    const float* ins   = (const float*)d_in[1];
    const int*   resets= (const int*)d_in[2];
    const float* W_emb = (const float*)d_in[3];
    const float* b_emb = (const float*)d_in[4];
    const float* Wq    = (const float*)d_in[5];
    const float* bq    = (const float*)d_in[6];
    const float* Wk    = (const float*)d_in[7];
    const float* bk    = (const float*)d_in[8];
    const float* Wv    = (const float*)d_in[9];
    const float* bv    = (const float*)d_in[10];
    const float* Wo    = (const float*)d_in[11];
    const float* bo    = (const float*)d_in[12];
    const float* ln1s  = (const float*)d_in[13];
    const float* ln1b  = (const float*)d_in[14];
    const float* ln2s  = (const float*)d_in[15];
    const float* ln2b  = (const float*)d_in[16];
    const float* W1    = (const float*)d_in[17];
    const float* b1    = (const float*)d_in[18];
    const float* W2    = (const float*)d_in[19];
    const float* b2    = (const float*)d_in[20];
    const float* Wqp   = (const float*)d_in[21];
    const float* bqp   = (const float*)d_in[22];
    float* out = (float*)d_out;
    char* ws  = (char*)d_ws;

    // ---- workspace layout (bytes), peak ~149.30 MB ----
    // xb   [32832][512]  bf16   @ 0            (33,619,968)
    // qkv  [32832][1536] bf16   @ 33,619,968   (100,859,904)
    //   f  [16416][2048] bf16   @ qkv+0        (67,239,936)   (FFN, qkv dead)
    //   y2 [32832][512]  bf16   @ qkv+67,239,936 (33,619,968) (exact fit)
    // WembT               @ 134,479,872  (131,072)
    // LW                  @ 134,610,944: WqkvT(1,572,864) WoT(524,288)
    //                       W1T(2,097,152) W2T(2,097,152) bqkv(6,144)
    // insb                @ 140,908,544  (8,388,608)  -> end 149,297,152
    bf16* xb   = (bf16*)(ws);
    bf16* qkv  = (bf16*)(ws + 33619968);
    bf16* f    = qkv;
    bf16* y2   = (bf16*)(ws + 33619968 + 67239936);
    bf16* WembT= (bf16*)(ws + 134479872);
    char* LW   = ws + 134610944;
    bf16* WqkvT= (bf16*)(LW + 0);
    bf16* WoT  = (bf16*)(LW + 1572864);
    bf16* W1T  = (bf16*)(LW + 2097152);
    bf16* W2T  = (bf16*)(LW + 4194304);
    float* bqkv= (float*)(LW + 6291456);
    bf16* insb = (bf16*)(ws + 140908544);

    cvt_bf16<<<4096, 256, 0, stream>>>(ins, insb, 4194304);
    transpose_f32<<<dim3(16, 4), 256, 0, stream>>>(W_emb, WembT, 128, 512, 0);
    build_x0<<<64, 256, 0, stream>>>(hs, resets, xb);
    gemm256<1, 0><<<dim3(2, 128), 512, 0, stream>>>(
        insb, WembT, b_emb, xb, 32768, 512, 128, 128, 512);

    for (int l = 0; l < 4; l++) {
        const long o512  = (long)l * 262144;
        const long o2048 = (long)l * 1048576;
        // fused QKV weight: rows [0,512)=Wq^T, [512,1024)=Wk^T, [1024,1536)=Wv^T
        transpose_f32<<<dim3(16, 16), 256, 0, stream>>>(Wq, WqkvT,          512, 512,  o512);
        transpose_f32<<<dim3(16, 16), 256, 0, stream>>>(Wk, WqkvT + 262144, 512, 512,  o512);
        transpose_f32<<<dim3(16, 16), 256, 0, stream>>>(Wv, WqkvT + 524288, 512, 512,  o512);
        transpose_f32<<<dim3(16, 16), 256, 0, stream>>>(Wo, WoT,            512, 512,  o512);
        transpose_f32<<<dim3(64, 16), 256, 0, stream>>>(W1, W1T,            512, 2048, o2048);
        transpose_f32<<<dim3(16, 64), 256, 0, stream>>>(W2, W2T,            2048, 512, o2048);
        concat3<<<6, 256, 0, stream>>>(bq + l * 512, bk + l * 512, bv + l * 512, bqkv);

        // fused QKV: qkv[row][1536], relu+eps on cols<1024 (q,k), none on v
        gemm256<0, 3><<<dim3(6, 129), 512, 0, stream>>>(
            xb, WqkvT, bqkv, qkv, 32832, 1536, 512, 512, 1536);
        favor_mfma<<<512, 256, 0, stream>>>(qkv);
        // O-proj: A = ao (pq slice of qkv, lda 1536), out y -> pk slice (ldc 1536)
        gemm256<0, 0><<<dim3(2, 129), 512, 0, stream>>>(
            qkv, WoT, bo + l * 512, qkv + 512, 32832, 512, 512, 1536, 1536);
        ln_res<<<8208, 256, 0, stream>>>(qkv + 512, 1536, ln1s + l * 512, ln1b + l * 512, xb);

        // FFN in two 16416-row chunks; f + y2 alias exactly inside qkv region
        for (int c = 0; c < 2; c++) {
            const long r0 = (long)c * 16416;
            gemm256<0, 1><<<dim3(8, 65), 512, 0, stream>>>(
                xb + r0 * 512, W1T, b1 + l * 2048, f, 16416, 2048, 512, 512, 2048);
            gemm256<0, 0><<<dim3(2, 65), 512, 0, stream>>>(
                f, W2T, b2 + l * 512, y2 + r0 * 512, 16416, 512, 2048, 2048, 512);
        }
        ln_res<<<8208, 256, 0, stream>>>(y2, 512, ln2s + l * 512, ln2b + l * 512, xb);
    }

    final_head<<<64, 256, 0, stream>>>(xb, Wqp, bqp, out);
}

// Round 7
// 2263.025 us; speedup vs baseline: 1.1545x; 1.1545x over previous
//
#include <hip/hip_runtime.h>

typedef __bf16 bf16;
typedef __bf16 bf16x8 __attribute__((ext_vector_type(8)));
typedef float  f32x4  __attribute__((ext_vector_type(4)));

// B=64, S=512, OBS=128, D=512, H=8, F=2048, L=4, A=16; rows M = B*513 = 32832
// R22: revert to R17 structure (best verified, 1906us) with two changes:
// (1) gemm128 BK 32->64, SINGLE-buffered 32KB LDS: same staged bytes but half
//     the barrier drains (the dominant stall; R16/R19/R20/R21 showed every
//     double-buffer/pipeline variant loses occupancy-TLP at these shapes).
//     FFN-down K=2048: 64->32 exposed-latency iters.  Epilogue/MFMA = exact
//     R17 (84-VGPR scalar, proven).
// (2) prep launches batched: QKVO transposes -> 1 kernel (z=0..3), W1+W2 -> 1
//     kernel (z-mapped, no idle blocks), all 4 layers' bias concat hoisted to
//     one upfront launch (buffer reuses dead WembT region).  7 -> 2 per layer.
// XCD swizzle, fused QKV, strided qkv, FFN chunking unchanged from R17.

__device__ __forceinline__ void cp16(const bf16* g, bf16* l)
{
    __builtin_amdgcn_global_load_lds(
        (const __attribute__((address_space(1))) void*)g,
        (__attribute__((address_space(3))) void*)l,
        16, 0, 0);
}

__global__ __launch_bounds__(256) void cvt_bf16(
    const float* __restrict__ src, bf16* __restrict__ dst, int n)
{
    for (int i = blockIdx.x * 256 + threadIdx.x; i < n; i += gridDim.x * 256)
        dst[i] = (bf16)src[i];
}

__global__ __launch_bounds__(256) void transpose_f32(
    const float* __restrict__ W, bf16* __restrict__ WT, int K, int N, long elemOff)
{
    __shared__ bf16 tile[32][33];
    const int bn = blockIdx.x * 32;
    const int bk = blockIdx.y * 32;
    const int tx = threadIdx.x & 31, ty = threadIdx.x >> 5;
    for (int r = 0; r < 32; r += 8)
        tile[ty + r][tx] = (bf16)W[elemOff + (long)(bk + ty + r) * N + (bn + tx)];
    __syncthreads();
    for (int r = 0; r < 32; r += 8)
        WT[(long)(bn + ty + r) * K + (bk + tx)] = tile[tx][ty + r];
}

// z=0..3 -> transpose 512x512 slice of {Wq,Wk,Wv,Wo}[layer] into
// {WqkvT+0, WqkvT+256K, WqkvT+512K, WoT}.
__global__ __launch_bounds__(256) void prep_qkvo(
    const float* __restrict__ Wq, const float* __restrict__ Wk,
    const float* __restrict__ Wv, const float* __restrict__ Wo,
    bf16* __restrict__ WqkvT, bf16* __restrict__ WoT, long elemOff)
{
    __shared__ bf16 tile[32][33];
    const int z = blockIdx.z;
    const float* W = (z == 0) ? Wq : (z == 1) ? Wk : (z == 2) ? Wv : Wo;
    bf16* WT = (z < 3) ? (WqkvT + (long)z * 262144) : WoT;
    const int bn = blockIdx.x * 32;
    const int bk = blockIdx.y * 32;
    const int tx = threadIdx.x & 31, ty = threadIdx.x >> 5;
    for (int r = 0; r < 32; r += 8)
        tile[ty + r][tx] = (bf16)W[elemOff + (long)(bk + ty + r) * 512 + (bn + tx)];
    __syncthreads();
    for (int r = 0; r < 32; r += 8)
        WT[(long)(bn + ty + r) * 512 + (bk + tx)] = tile[tx][ty + r];
}

// z=0: W1 [512][2048] -> W1T [2048][512]   (bn=bx*32 over N=2048, bk=by*32 over K=512)
// z=1: W2 [2048][512] -> W2T [512][2048]   (bn=by*32 over N=512,  bk=bx*32 over K=2048)
__global__ __launch_bounds__(256) void prep_ffn(
    const float* __restrict__ W1, const float* __restrict__ W2,
    bf16* __restrict__ W1T, bf16* __restrict__ W2T, long elemOff)
{
    __shared__ bf16 tile[32][33];
    const int z = blockIdx.z;
    const float* W = z ? W2 : W1;
    bf16* WT = z ? W2T : W1T;
    const int N = z ? 512 : 2048;
    const int K = z ? 2048 : 512;
    const int bn = (z ? blockIdx.y : blockIdx.x) * 32;
    const int bk = (z ? blockIdx.x : blockIdx.y) * 32;
    const int tx = threadIdx.x & 31, ty = threadIdx.x >> 5;
    for (int r = 0; r < 32; r += 8)
        tile[ty + r][tx] = (bf16)W[elemOff + (long)(bk + ty + r) * N + (bn + tx)];
    __syncthreads();
    for (int r = 0; r < 32; r += 8)
        WT[(long)(bn + ty + r) * K + (bk + tx)] = tile[tx][ty + r];
}

// all 4 layers' {bq,bk,bv} -> bqkv_all[l][1536] in one launch (24 blocks)
__global__ __launch_bounds__(256) void concat_all(
    const float* __restrict__ bq, const float* __restrict__ bk,
    const float* __restrict__ bv, float* __restrict__ dst)
{
    const int i = blockIdx.x * 256 + threadIdx.x;   // 0..6143
    const int l = i >> 11;                           // /2048? no: 1536/l... 
    // i = l*1536 + c  done explicitly to avoid div:
    int rem = i;
    int lay = 0;
    while (rem >= 1536) { rem -= 1536; lay++; }      // <=3 iterations, uniform-ish
    if (lay > 3) return;
    float v;
    if (rem < 512)        v = bq[lay * 512 + rem];
    else if (rem < 1024)  v = bk[lay * 512 + rem - 512];
    else                  v = bv[lay * 512 + rem - 1024];
    dst[lay * 1536 + rem] = v;
    (void)l;
}

__global__ __launch_bounds__(256) void build_x0(
    const float* __restrict__ hs, const int* __restrict__ resets,
    bf16* __restrict__ xb)
{
    const int b = blockIdx.x;
    const bool rz = (resets[b] != 0);
    const long base = (long)b * 513 * 512;
    for (int d = threadIdx.x; d < 512; d += 256)
        xb[base + d] = rz ? (bf16)0.f : (bf16)hs[b * 512 + d];
}

// GEMM: C[M,N] = A[M,K] @ BT[N,K]^T + bias(fp32).  128x128 tile, BK=64,
// single-buffered 32KB LDS, 4 waves x (4x4) 16x16x32 MFMA, global_load_lds
// (16B) direct-to-LDS.  LDS UNPADDED [128][64] (DMA lane-order: wave w issue
// i deposits rows w*32+i*8+(l>>3), k-seg (l&7)*8 at elem w*2048+i*512+l*8 =
// row*64 + k).  K%64==0, N%128==0; M tail via overlap clamp.  A row stride
// lda, C row stride ldc.  Bijective XCD swizzle (m204).
// ROWMAP==1: row += row/512 + 1.  ACT: 0=none 1=relu 2=relu+eps 3=relu+eps iff col<1024.
template<int ROWMAP, int ACT>
__global__ __launch_bounds__(256) void gemm128(
    const bf16* __restrict__ A, const bf16* __restrict__ BT,
    const float* __restrict__ bias, bf16* __restrict__ outB,
    int M, int N, int K, int lda, int ldc)
{
    __shared__ bf16 As[128 * 64];
    __shared__ bf16 Bs[128 * 64];
    const int tid  = threadIdx.x;
    const int wave = tid >> 6;
    const int lane = tid & 63;
    const int q    = lane >> 4;
    const int lm   = lane & 15;
    const int wr   = wave >> 1, wc = wave & 1;

    // bijective XCD swizzle (m204): orig%8 = XCD slot -> contiguous partition
    int flat;
    {
        const int nwg  = gridDim.x * gridDim.y;
        const int orig = blockIdx.y * gridDim.x + blockIdx.x;
        const int qq = nwg >> 3, rr = nwg & 7;
        const int xcd = orig & 7, idx = orig >> 3;
        flat = (xcd < rr ? xcd * (qq + 1) : rr * (qq + 1) + (xcd - rr) * qq) + idx;
    }
    const int bx = flat % gridDim.x;
    const int by = flat / gridDim.x;
    int m0 = by * 128;
    if (m0 > M - 128) m0 = M - 128;            // tail overlap clamp
    const int n0 = bx * 128;

    // staging geometry (see header): 4 issues A + 4 issues B per wave per iter
    const int srow = lane >> 3;
    const int scol = (lane & 7) * 8;
    const bf16* Ag = A  + (long)(m0 + wave * 32 + srow) * lda + scol;
    const bf16* Bg = BT + (long)(n0 + wave * 32 + srow) * K   + scol;
    const long lda8 = (long)lda * 8;
    const long K8   = (long)K * 8;
    bf16* Al = As + wave * 2048;
    bf16* Bl = Bs + wave * 2048;

    f32x4 acc[4][4];
    for (int i = 0; i < 4; i++) for (int j = 0; j < 4; j++)
        for (int r = 0; r < 4; r++) acc[i][j][r] = 0.f;

    for (int k0 = 0; k0 < K; k0 += 64) {
        #pragma unroll
        for (int i = 0; i < 4; i++) {
            cp16(Ag + i * lda8 + k0, Al + i * 512);
            cp16(Bg + i * K8   + k0, Bl + i * 512);
        }
        __syncthreads();                       // drains vmcnt -> DMA landed
        #pragma unroll
        for (int ks = 0; ks < 2; ks++) {
            bf16x8 af[4], bfr[4];
            #pragma unroll
            for (int i = 0; i < 4; i++)
                af[i] = *(const bf16x8*)(As + (wr * 64 + i * 16 + lm) * 64 + ks * 32 + q * 8);
            #pragma unroll
            for (int j = 0; j < 4; j++)
                bfr[j] = *(const bf16x8*)(Bs + (wc * 64 + j * 16 + lm) * 64 + ks * 32 + q * 8);
            #pragma unroll
            for (int i = 0; i < 4; i++)
                #pragma unroll
                for (int j = 0; j < 4; j++)
                    acc[i][j] = __builtin_amdgcn_mfma_f32_16x16x32_bf16(
                        af[i], bfr[j], acc[i][j], 0, 0, 0);
        }
        __syncthreads();                       // LDS safe for next DMA
    }

    // C/D: col = lane&15, row = (lane>>4)*4 + r  [session-verified]
    #pragma unroll
    for (int j = 0; j < 4; j++) {
        const int col = n0 + wc * 64 + j * 16 + lm;
        const float bv = bias[col];
        #pragma unroll
        for (int i = 0; i < 4; i++) {
            #pragma unroll
            for (int r = 0; r < 4; r++) {
                int row = m0 + wr * 64 + i * 16 + q * 4 + r;
                float vv = acc[i][j][r] + bv;
                if (ACT == 1) vv = fmaxf(vv, 0.f);
                if (ACT == 2) vv = fmaxf(vv, 0.f) + 1e-3f;
                if (ACT == 3 && col < 1024) vv = fmaxf(vv, 0.f) + 1e-3f;
                if (ROWMAP == 1) row = row + (row >> 9) + 1;
                outB[(long)row * ldc + col] = (bf16)vv;
            }
        }
    }
}

// FAVOR+ attention, full MFMA.  Reads pq/pk/vv as column slices {0,512,1024}
// of the strided qkv[row][1536] buffer; writes ao back into the pq slice
// (per-(b,h) alias safe: each t8 tile's pq rows are staged before overwrite).
#define FP 72
__global__ __launch_bounds__(256) void favor_mfma(bf16* qkv)
{
    const int bh = blockIdx.x;
    const int b = bh >> 3, h = bh & 7;
    const long rbQ = (long)b * 513 * 1536 + h * 64;
    const long rbK = rbQ + 512;
    const long rbV = rbQ + 1024;

    __shared__ bf16 pkT[64][FP];
    __shared__ bf16 vT [64][FP];
    __shared__ bf16 kvT[64][FP];
    __shared__ bf16 pqS[64][FP];
    __shared__ float ksumS[64];
    __shared__ float denS[64];

    const int tid  = threadIdx.x;
    const int wave = tid >> 6;
    const int lane = tid & 63;
    const int q    = lane >> 4;
    const int lm   = lane & 15;
    const int wr   = wave >> 1, wc = wave & 1;
    const int mp   = (tid & 31) * 2;
    const int sr   = tid >> 5;

    if (tid < 64) ksumS[tid] = 0.f;
    float ksp0 = 0.f, ksp1 = 0.f;

    f32x4 akv[2][2];
    for (int i = 0; i < 2; i++) for (int j = 0; j < 2; j++)
        for (int r = 0; r < 4; r++) akv[i][j][r] = 0.f;

    for (int t8 = 0; t8 < 9; t8++) {
        const int s0 = t8 * 64;
        #pragma unroll
        for (int i = 0; i < 8; i++) {
            const int s  = sr + i * 8;
            const int gs = s0 + s;
            unsigned pkw = 0, vw = 0;
            if (gs < 513) {
                pkw = *(const unsigned*)(qkv + rbK + (long)gs * 1536 + mp);
                vw  = *(const unsigned*)(qkv + rbV + (long)gs * 1536 + mp);
            }
            union { unsigned u; bf16 hh[2]; } pu, vu;
            pu.u = pkw; vu.u = vw;
            pkT[mp][s]     = pu.hh[0];
            pkT[mp + 1][s] = pu.hh[1];
            vT[mp][s]      = vu.hh[0];
            vT[mp + 1][s]  = vu.hh[1];
            ksp0 += (float)pu.hh[0];
            ksp1 += (float)pu.hh[1];
        }
        __syncthreads();
        #pragma unroll
        for (int ks = 0; ks < 2; ks++) {
            bf16x8 a0 = *(const bf16x8*)(&pkT[wr * 32 + lm     ][ks * 32 + q * 8]);
            bf16x8 a1 = *(const bf16x8*)(&pkT[wr * 32 + 16 + lm][ks * 32 + q * 8]);
            bf16x8 b0 = *(const bf16x8*)(&vT [wc * 32 + lm     ][ks * 32 + q * 8]);
            bf16x8 b1 = *(const bf16x8*)(&vT [wc * 32 + 16 + lm][ks * 32 + q * 8]);
            akv[0][0] = __builtin_amdgcn_mfma_f32_16x16x32_bf16(a0, b0, akv[0][0], 0, 0, 0);
            akv[0][1] = __builtin_amdgcn_mfma_f32_16x16x32_bf16(a0, b1, akv[0][1], 0, 0, 0);
            akv[1][0] = __builtin_amdgcn_mfma_f32_16x16x32_bf16(a1, b0, akv[1][0], 0, 0, 0);
            akv[1][1] = __builtin_amdgcn_mfma_f32_16x16x32_bf16(a1, b1, akv[1][1], 0, 0, 0);
        }
        __syncthreads();
    }
    atomicAdd(&ksumS[mp],     ksp0);
    atomicAdd(&ksumS[mp + 1], ksp1);
    #pragma unroll
    for (int i = 0; i < 2; i++)
        #pragma unroll
        for (int j = 0; j < 2; j++)
            #pragma unroll
            for (int r = 0; r < 4; r++)
                kvT[wc * 32 + j * 16 + lm][wr * 32 + i * 16 + q * 4 + r] =
                    (bf16)akv[i][j][r];
    __syncthreads();

    const int prow = tid >> 2;
    const int pseg = (tid & 3) * 16;
    for (int t8 = 0; t8 < 9; t8++) {
        const int s0 = t8 * 64;
        const int gs = s0 + prow;
        if (gs < 513) {
            *(bf16x8*)(&pqS[prow][pseg])     = *(const bf16x8*)(qkv + rbQ + (long)gs * 1536 + pseg);
            *(bf16x8*)(&pqS[prow][pseg + 8]) = *(const bf16x8*)(qkv + rbQ + (long)gs * 1536 + pseg + 8);
        } else {
            bf16x8 z;
            for (int r = 0; r < 8; r++) z[r] = (bf16)0.f;
            *(bf16x8*)(&pqS[prow][pseg])     = z;
            *(bf16x8*)(&pqS[prow][pseg + 8]) = z;
        }
        __syncthreads();
        {
            const int s = tid >> 2, mb = (tid & 3) * 16;
            float dp = 0.f;
            #pragma unroll
            for (int m2 = 0; m2 < 16; m2++)
                dp += (float)pqS[s][mb + m2] * ksumS[mb + m2];
            dp += __shfl_xor(dp, 1);
            dp += __shfl_xor(dp, 2);
            if ((tid & 3) == 0) denS[s] = dp;
        }
        __syncthreads();
        f32x4 an[4];
        for (int j = 0; j < 4; j++)
            for (int r = 0; r < 4; r++) an[j][r] = 0.f;
        #pragma unroll
        for (int ks = 0; ks < 2; ks++) {
            bf16x8 a = *(const bf16x8*)(&pqS[wave * 16 + lm][ks * 32 + q * 8]);
            #pragma unroll
            for (int j = 0; j < 4; j++) {
                bf16x8 bb = *(const bf16x8*)(&kvT[j * 16 + lm][ks * 32 + q * 8]);
                an[j] = __builtin_amdgcn_mfma_f32_16x16x32_bf16(a, bb, an[j], 0, 0, 0);
            }
        }
        #pragma unroll
        for (int j = 0; j < 4; j++) {
            #pragma unroll
            for (int r = 0; r < 4; r++) {
                const int sl  = wave * 16 + q * 4 + r;
                const int gs2 = s0 + sl;
                if (gs2 < 513) {
                    const int d = j * 16 + lm;
                    qkv[rbQ + (long)gs2 * 1536 + d] = (bf16)(an[j][r] / denS[sl]);
                }
            }
        }
        __syncthreads();
    }
}

__global__ __launch_bounds__(256) void ln_res(
    const bf16* __restrict__ y, int ldy, const float* __restrict__ sc,
    const float* __restrict__ bi, bf16* __restrict__ xb)
{
    const int row  = blockIdx.x * 4 + (threadIdx.x >> 6);
    const int lane = threadIdx.x & 63;
    const bf16* yr = y  + (long)row * ldy + lane * 8;
    bf16*       xr = xb + (long)row * 512 + lane * 8;
    bf16x8 yv = *(const bf16x8*)yr;
    bf16x8 xv = *(const bf16x8*)xr;
    float v[8];
    float sum = 0.f;
    #pragma unroll
    for (int i = 0; i < 8; i++) { v[i] = (float)yv[i] + (float)xv[i]; sum += v[i]; }
    #pragma unroll
    for (int o = 32; o; o >>= 1) sum += __shfl_xor(sum, o);
    const float mean = sum * (1.f / 512.f);
    float vs = 0.f;
    #pragma unroll
    for (int i = 0; i < 8; i++) { float dd = v[i] - mean; vs += dd * dd; }
    #pragma unroll
    for (int o = 32; o; o >>= 1) vs += __shfl_xor(vs, o);
    const float rstd = rsqrtf(vs * (1.f / 512.f) + 1e-6f);
    bf16x8 ov;
    #pragma unroll
    for (int i = 0; i < 8; i++)
        ov[i] = (bf16)((v[i] - mean) * rstd * sc[lane * 8 + i] + bi[lane * 8 + i]);
    *(bf16x8*)xr = ov;
}

__global__ __launch_bounds__(256) void final_head(
    const bf16* __restrict__ xb, const float* __restrict__ Wqp,
    const float* __restrict__ bqp, float* __restrict__ out)
{
    const int b = blockIdx.x;
    const bf16* xr = xb + (long)b * 513 * 512;
    for (int i = threadIdx.x; i < 512; i += 256) out[b * 512 + i] = (float)xr[i];
    const int a = threadIdx.x & 15, g = threadIdx.x >> 4;
    float p = 0.f;
    for (int k = g * 32; k < g * 32 + 32; k++)
        p += (float)xr[k] * Wqp[k * 16 + a];
    __shared__ float red[256];
    red[threadIdx.x] = p;
    __syncthreads();
    if (threadIdx.x < 16) {
        float s = bqp[a];
        for (int g2 = 0; g2 < 16; g2++) s += red[g2 * 16 + a];
        out[64 * 512 + b * 16 + a] = s;
    }
}

extern "C" void kernel_launch(void* const* d_in, const int* in_sizes, int n_in,
                              void* d_out, int out_size, void* d_ws, size_t ws_size,
                              hipStream_t stream)
{
    (void)in_sizes; (void)n_in; (void)out_size; (void)ws_size;
    const float* hs    = (const float*)d_in[0];
    const float* ins   = (const float*)d_in[1];
    const int*   resets= (const int*)d_in[2];
    const float* W_emb = (const float*)d_in[3];
    const float* b_emb = (const float*)d_in[4];
    const float* Wq    = (const float*)d_in[5];
    const float* bq    = (const float*)d_in[6];
    const float* Wk    = (const float*)d_in[7];
    const float* bk    = (const float*)d_in[8];
    const float* Wv    = (const float*)d_in[9];
    const float* bv    = (const float*)d_in[10];
    const float* Wo    = (const float*)d_in[11];
    const float* bo    = (const float*)d_in[12];
    const float* ln1s  = (const float*)d_in[13];
    const float* ln1b  = (const float*)d_in[14];
    const float* ln2s  = (const float*)d_in[15];
    const float* ln2b  = (const float*)d_in[16];
    const float* W1    = (const float*)d_in[17];
    const float* b1    = (const float*)d_in[18];
    const float* W2    = (const float*)d_in[19];
    const float* b2    = (const float*)d_in[20];
    const float* Wqp   = (const float*)d_in[21];
    const float* bqp   = (const float*)d_in[22];
    float* out = (float*)d_out;
    char* ws  = (char*)d_ws;

    // ---- workspace layout (bytes), peak ~149.30 MB ----
    // xb   [32832][512]  bf16   @ 0            (33,619,968)
    // qkv  [32832][1536] bf16   @ 33,619,968   (100,859,904)
    //   f  [16416][2048] bf16   @ qkv+0        (67,239,936)   (FFN, qkv dead)
    //   y2 [32832][512]  bf16   @ qkv+67,239,936 (33,619,968) (exact fit)
    // WembT               @ 134,479,872  (131,072)  -> reused as bqkv_all after embed
    // LW                  @ 134,610,944: WqkvT(1,572,864) WoT(524,288)
    //                       W1T(2,097,152) W2T(2,097,152)
    // insb                @ 140,908,544  (8,388,608)  -> end 149,297,152
    bf16* xb   = (bf16*)(ws);
    bf16* qkv  = (bf16*)(ws + 33619968);
    bf16* f    = qkv;
    bf16* y2   = (bf16*)(ws + 33619968 + 67239936);
    bf16* WembT= (bf16*)(ws + 134479872);
    float* bqkv_all = (float*)(ws + 134479872);   // 24KB, reuses WembT after embed
    char* LW   = ws + 134610944;
    bf16* WqkvT= (bf16*)(LW + 0);
    bf16* WoT  = (bf16*)(LW + 1572864);
    bf16* W1T  = (bf16*)(LW + 2097152);
    bf16* W2T  = (bf16*)(LW + 4194304);
    bf16* insb = (bf16*)(ws + 140908544);

    cvt_bf16<<<4096, 256, 0, stream>>>(ins, insb, 4194304);
    transpose_f32<<<dim3(16, 4), 256, 0, stream>>>(W_emb, WembT, 128, 512, 0);
    build_x0<<<64, 256, 0, stream>>>(hs, resets, xb);
    gemm128<1, 0><<<dim3(4, 256), 256, 0, stream>>>(
        insb, WembT, b_emb, xb, 32768, 512, 128, 128, 512);
    // WembT dead from here; bqkv_all takes the region
    concat_all<<<24, 256, 0, stream>>>(bq, bk, bv, bqkv_all);

    for (int l = 0; l < 4; l++) {
        const long o512  = (long)l * 262144;
        const long o2048 = (long)l * 1048576;
        prep_qkvo<<<dim3(16, 16, 4), 256, 0, stream>>>(Wq, Wk, Wv, Wo, WqkvT, WoT, o512);
        prep_ffn<<<dim3(64, 16, 2), 256, 0, stream>>>(W1, W2, W1T, W2T, o2048);

        // fused QKV: qkv[row][1536], relu+eps on cols<1024 (q,k), none on v
        gemm128<0, 3><<<dim3(12, 257), 256, 0, stream>>>(
            xb, WqkvT, bqkv_all + l * 1536, qkv, 32832, 1536, 512, 512, 1536);
        favor_mfma<<<512, 256, 0, stream>>>(qkv);
        // O-proj: A = ao (pq slice of qkv, lda 1536), out y -> pk slice (ldc 1536)
        gemm128<0, 0><<<dim3(4, 257), 256, 0, stream>>>(
            qkv, WoT, bo + l * 512, qkv + 512, 32832, 512, 512, 1536, 1536);
        ln_res<<<8208, 256, 0, stream>>>(qkv + 512, 1536, ln1s + l * 512, ln1b + l * 512, xb);

        // FFN in two 16416-row chunks; f + y2 alias exactly inside qkv region
        for (int c = 0; c < 2; c++) {
            const long r0 = (long)c * 16416;
            gemm128<0, 1><<<dim3(16, 129), 256, 0, stream>>>(
                xb + r0 * 512, W1T, b1 + l * 2048, f, 16416, 2048, 512, 512, 2048);
            gemm128<0, 0><<<dim3(4, 129), 256, 0, stream>>>(
                f, W2T, b2 + l * 512, y2 + r0 * 512, 16416, 512, 2048, 2048, 512);
        }
        ln_res<<<8208, 256, 0, stream>>>(y2, 512, ln2s + l * 512, ln2b + l * 512, xb);
    }

    final_head<<<64, 256, 0, stream>>>(xb, Wqp, bqp, out);
}

// Round 8
// 1891.522 us; speedup vs baseline: 1.3813x; 1.1964x over previous
//
#include <hip/hip_runtime.h>

typedef __bf16 bf16;
typedef __bf16 bf16x8 __attribute__((ext_vector_type(8)));
typedef float  f32x4  __attribute__((ext_vector_type(4)));

// B=64, S=512, OBS=128, D=512, H=8, F=2048, L=4, A=16; rows M = B*513 = 32832
// R23 = exact R17 gemm structure (best verified, 1906us: BK=32, 16KB
// single-buffer LDS, un-swapped MFMA, scalar epilogue, 84 VGPR) plus two
// orthogonal fixes:
// (1) T2 both-sides XOR swizzle (rule #21) on the [128][32] LDS tiles:
//     global source k-seg ksw = ((l&3)^((l>>2)&3))*8, LDS read seg
//     qx = (q^(lm&3))*8.  Physical (row,kp) holds logical kp^(row&3); read
//     recovers seg q.  8-way -> 4-way bank conflict (R22 confirmed the bank
//     model: 128B rows tripled the conflict counter).  DMA dest stays linear.
// (2) R22's batched preps (proven orthogonal): prep_qkvo z=0..3, prep_ffn
//     z=0..1, concat_all hoisted upfront.  7 -> 2 launches/layer.

__device__ __forceinline__ void cp16(const bf16* g, bf16* l)
{
    __builtin_amdgcn_global_load_lds(
        (const __attribute__((address_space(1))) void*)g,
        (__attribute__((address_space(3))) void*)l,
        16, 0, 0);
}

__global__ __launch_bounds__(256) void cvt_bf16(
    const float* __restrict__ src, bf16* __restrict__ dst, int n)
{
    for (int i = blockIdx.x * 256 + threadIdx.x; i < n; i += gridDim.x * 256)
        dst[i] = (bf16)src[i];
}

__global__ __launch_bounds__(256) void transpose_f32(
    const float* __restrict__ W, bf16* __restrict__ WT, int K, int N, long elemOff)
{
    __shared__ bf16 tile[32][33];
    const int bn = blockIdx.x * 32;
    const int bk = blockIdx.y * 32;
    const int tx = threadIdx.x & 31, ty = threadIdx.x >> 5;
    for (int r = 0; r < 32; r += 8)
        tile[ty + r][tx] = (bf16)W[elemOff + (long)(bk + ty + r) * N + (bn + tx)];
    __syncthreads();
    for (int r = 0; r < 32; r += 8)
        WT[(long)(bn + ty + r) * K + (bk + tx)] = tile[tx][ty + r];
}

// z=0..3 -> transpose 512x512 slice of {Wq,Wk,Wv,Wo}[layer] into
// {WqkvT+0, WqkvT+256K, WqkvT+512K, WoT}.
__global__ __launch_bounds__(256) void prep_qkvo(
    const float* __restrict__ Wq, const float* __restrict__ Wk,
    const float* __restrict__ Wv, const float* __restrict__ Wo,
    bf16* __restrict__ WqkvT, bf16* __restrict__ WoT, long elemOff)
{
    __shared__ bf16 tile[32][33];
    const int z = blockIdx.z;
    const float* W = (z == 0) ? Wq : (z == 1) ? Wk : (z == 2) ? Wv : Wo;
    bf16* WT = (z < 3) ? (WqkvT + (long)z * 262144) : WoT;
    const int bn = blockIdx.x * 32;
    const int bk = blockIdx.y * 32;
    const int tx = threadIdx.x & 31, ty = threadIdx.x >> 5;
    for (int r = 0; r < 32; r += 8)
        tile[ty + r][tx] = (bf16)W[elemOff + (long)(bk + ty + r) * 512 + (bn + tx)];
    __syncthreads();
    for (int r = 0; r < 32; r += 8)
        WT[(long)(bn + ty + r) * 512 + (bk + tx)] = tile[tx][ty + r];
}

// z=0: W1 [512][2048] -> W1T [2048][512];  z=1: W2 [2048][512] -> W2T [512][2048]
__global__ __launch_bounds__(256) void prep_ffn(
    const float* __restrict__ W1, const float* __restrict__ W2,
    bf16* __restrict__ W1T, bf16* __restrict__ W2T, long elemOff)
{
    __shared__ bf16 tile[32][33];
    const int z = blockIdx.z;
    const float* W = z ? W2 : W1;
    bf16* WT = z ? W2T : W1T;
    const int N = z ? 512 : 2048;
    const int K = z ? 2048 : 512;
    const int bn = (z ? blockIdx.y : blockIdx.x) * 32;
    const int bk = (z ? blockIdx.x : blockIdx.y) * 32;
    const int tx = threadIdx.x & 31, ty = threadIdx.x >> 5;
    for (int r = 0; r < 32; r += 8)
        tile[ty + r][tx] = (bf16)W[elemOff + (long)(bk + ty + r) * N + (bn + tx)];
    __syncthreads();
    for (int r = 0; r < 32; r += 8)
        WT[(long)(bn + ty + r) * K + (bk + tx)] = tile[tx][ty + r];
}

// all 4 layers' {bq,bk,bv} -> bqkv_all[l][1536] in one launch (24 blocks)
__global__ __launch_bounds__(256) void concat_all(
    const float* __restrict__ bq, const float* __restrict__ bk,
    const float* __restrict__ bv, float* __restrict__ dst)
{
    const int i = blockIdx.x * 256 + threadIdx.x;   // 0..6143
    if (i >= 6144) return;
    const int lay = i / 1536;
    const int rem = i - lay * 1536;
    float v;
    if (rem < 512)        v = bq[lay * 512 + rem];
    else if (rem < 1024)  v = bk[lay * 512 + rem - 512];
    else                  v = bv[lay * 512 + rem - 1024];
    dst[lay * 1536 + rem] = v;
}

__global__ __launch_bounds__(256) void build_x0(
    const float* __restrict__ hs, const int* __restrict__ resets,
    bf16* __restrict__ xb)
{
    const int b = blockIdx.x;
    const bool rz = (resets[b] != 0);
    const long base = (long)b * 513 * 512;
    for (int d = threadIdx.x; d < 512; d += 256)
        xb[base + d] = rz ? (bf16)0.f : (bf16)hs[b * 512 + d];
}

// GEMM: C[M,N] = A[M,K] @ BT[N,K]^T + bias(fp32).  128x128 tile, BK=32,
// 4 waves x (4x4) 16x16x32 MFMA, global_load_lds(16B) direct-to-LDS staging.
// LDS [128][32] linear dest; T2 XOR swizzle via pre-swizzled GLOBAL source
// (ksw) + swizzled read seg (qx) -- see file header.  N%128==0; M tail via
// overlap clamp.  A row stride lda, C row stride ldc.  Bijective XCD swizzle.
// ROWMAP==1: row += row/512 + 1.  ACT: 0=none 1=relu 2=relu+eps 3=relu+eps iff col<1024.
template<int ROWMAP, int ACT>
__global__ __launch_bounds__(256) void gemm128(
    const bf16* __restrict__ A, const bf16* __restrict__ BT,
    const float* __restrict__ bias, bf16* __restrict__ outB,
    int M, int N, int K, int lda, int ldc)
{
    __shared__ bf16 As[128 * 32];
    __shared__ bf16 Bs[128 * 32];
    const int tid  = threadIdx.x;
    const int wave = tid >> 6;
    const int lane = tid & 63;
    const int q    = lane >> 4;
    const int lm   = lane & 15;
    const int wr   = wave >> 1, wc = wave & 1;

    // bijective XCD swizzle (m204): orig%8 = XCD slot -> contiguous partition
    int flat;
    {
        const int nwg  = gridDim.x * gridDim.y;
        const int orig = blockIdx.y * gridDim.x + blockIdx.x;
        const int qq = nwg >> 3, rr = nwg & 7;
        const int xcd = orig & 7, idx = orig >> 3;
        flat = (xcd < rr ? xcd * (qq + 1) : rr * (qq + 1) + (xcd - rr) * qq) + idx;
    }
    const int bx = flat % gridDim.x;
    const int by = flat / gridDim.x;
    int m0 = by * 128;
    if (m0 > M - 128) m0 = M - 128;            // tail overlap clamp
    const int n0 = bx * 128;

    // staging geometry: wave w issue i deposits rows w*32+i*16+(l>>2) at
    // linear LDS slot l (elem row*32 + (l&3)*8).  T2: lane fetches k-seg
    // (l&3)^((l>>2)&3) so physical (row,kp) holds logical kp^(row&3).
    const int r0  = wave * 32 + (lane >> 2);
    const int ksw = ((lane & 3) ^ ((lane >> 2) & 3)) * 8;
    const bf16* Ag0 = A  + (long)(m0 + r0) * lda + ksw;
    const bf16* Ag1 = A  + (long)(m0 + r0 + 16) * lda + ksw;
    const bf16* Bg0 = BT + (long)(n0 + r0) * K + ksw;
    const bf16* Bg1 = BT + (long)(n0 + r0 + 16) * K + ksw;
    bf16* Al0 = As + wave * 1024;
    bf16* Al1 = As + wave * 1024 + 512;
    bf16* Bl0 = Bs + wave * 1024;
    bf16* Bl1 = Bs + wave * 1024 + 512;

    // read-side swizzle: logical seg q lives at physical q^(row&3), row&3 = lm&3
    const int qx = (q ^ (lm & 3)) * 8;

    f32x4 acc[4][4];
    for (int i = 0; i < 4; i++) for (int j = 0; j < 4; j++)
        for (int r = 0; r < 4; r++) acc[i][j][r] = 0.f;

    for (int k0 = 0; k0 < K; k0 += 32) {
        cp16(Ag0 + k0, Al0);
        cp16(Ag1 + k0, Al1);
        cp16(Bg0 + k0, Bl0);
        cp16(Bg1 + k0, Bl1);
        __syncthreads();                       // drains vmcnt -> DMA landed
        bf16x8 af[4], bfr[4];
        #pragma unroll
        for (int i = 0; i < 4; i++)
            af[i] = *(const bf16x8*)(As + (wr * 64 + i * 16 + lm) * 32 + qx);
        #pragma unroll
        for (int j = 0; j < 4; j++)
            bfr[j] = *(const bf16x8*)(Bs + (wc * 64 + j * 16 + lm) * 32 + qx);
        #pragma unroll
        for (int i = 0; i < 4; i++)
            #pragma unroll
            for (int j = 0; j < 4; j++)
                acc[i][j] = __builtin_amdgcn_mfma_f32_16x16x32_bf16(
                    af[i], bfr[j], acc[i][j], 0, 0, 0);
        __syncthreads();                       // LDS safe for next DMA
    }

    // C/D: col = lane&15, row = (lane>>4)*4 + r  [session-verified]
    #pragma unroll
    for (int j = 0; j < 4; j++) {
        const int col = n0 + wc * 64 + j * 16 + lm;
        const float bv = bias[col];
        #pragma unroll
        for (int i = 0; i < 4; i++) {
            #pragma unroll
            for (int r = 0; r < 4; r++) {
                int row = m0 + wr * 64 + i * 16 + q * 4 + r;
                float vv = acc[i][j][r] + bv;
                if (ACT == 1) vv = fmaxf(vv, 0.f);
                if (ACT == 2) vv = fmaxf(vv, 0.f) + 1e-3f;
                if (ACT == 3 && col < 1024) vv = fmaxf(vv, 0.f) + 1e-3f;
                if (ROWMAP == 1) row = row + (row >> 9) + 1;
                outB[(long)row * ldc + col] = (bf16)vv;
            }
        }
    }
}

// FAVOR+ attention, full MFMA.  Reads pq/pk/vv as column slices {0,512,1024}
// of the strided qkv[row][1536] buffer; writes ao back into the pq slice
// (per-(b,h) alias safe: each t8 tile's pq rows are staged before overwrite).
#define FP 72
__global__ __launch_bounds__(256) void favor_mfma(bf16* qkv)
{
    const int bh = blockIdx.x;
    const int b = bh >> 3, h = bh & 7;
    const long rbQ = (long)b * 513 * 1536 + h * 64;
    const long rbK = rbQ + 512;
    const long rbV = rbQ + 1024;

    __shared__ bf16 pkT[64][FP];
    __shared__ bf16 vT [64][FP];
    __shared__ bf16 kvT[64][FP];
    __shared__ bf16 pqS[64][FP];
    __shared__ float ksumS[64];
    __shared__ float denS[64];

    const int tid  = threadIdx.x;
    const int wave = tid >> 6;
    const int lane = tid & 63;
    const int q    = lane >> 4;
    const int lm   = lane & 15;
    const int wr   = wave >> 1, wc = wave & 1;
    const int mp   = (tid & 31) * 2;
    const int sr   = tid >> 5;

    if (tid < 64) ksumS[tid] = 0.f;
    float ksp0 = 0.f, ksp1 = 0.f;

    f32x4 akv[2][2];
    for (int i = 0; i < 2; i++) for (int j = 0; j < 2; j++)
        for (int r = 0; r < 4; r++) akv[i][j][r] = 0.f;

    for (int t8 = 0; t8 < 9; t8++) {
        const int s0 = t8 * 64;
        #pragma unroll
        for (int i = 0; i < 8; i++) {
            const int s  = sr + i * 8;
            const int gs = s0 + s;
            unsigned pkw = 0, vw = 0;
            if (gs < 513) {
                pkw = *(const unsigned*)(qkv + rbK + (long)gs * 1536 + mp);
                vw  = *(const unsigned*)(qkv + rbV + (long)gs * 1536 + mp);
            }
            union { unsigned u; bf16 hh[2]; } pu, vu;
            pu.u = pkw; vu.u = vw;
            pkT[mp][s]     = pu.hh[0];
            pkT[mp + 1][s] = pu.hh[1];
            vT[mp][s]      = vu.hh[0];
            vT[mp + 1][s]  = vu.hh[1];
            ksp0 += (float)pu.hh[0];
            ksp1 += (float)pu.hh[1];
        }
        __syncthreads();
        #pragma unroll
        for (int ks = 0; ks < 2; ks++) {
            bf16x8 a0 = *(const bf16x8*)(&pkT[wr * 32 + lm     ][ks * 32 + q * 8]);
            bf16x8 a1 = *(const bf16x8*)(&pkT[wr * 32 + 16 + lm][ks * 32 + q * 8]);
            bf16x8 b0 = *(const bf16x8*)(&vT [wc * 32 + lm     ][ks * 32 + q * 8]);
            bf16x8 b1 = *(const bf16x8*)(&vT [wc * 32 + 16 + lm][ks * 32 + q * 8]);
            akv[0][0] = __builtin_amdgcn_mfma_f32_16x16x32_bf16(a0, b0, akv[0][0], 0, 0, 0);
            akv[0][1] = __builtin_amdgcn_mfma_f32_16x16x32_bf16(a0, b1, akv[0][1], 0, 0, 0);
            akv[1][0] = __builtin_amdgcn_mfma_f32_16x16x32_bf16(a1, b0, akv[1][0], 0, 0, 0);
            akv[1][1] = __builtin_amdgcn_mfma_f32_16x16x32_bf16(a1, b1, akv[1][1], 0, 0, 0);
        }
        __syncthreads();
    }
    atomicAdd(&ksumS[mp],     ksp0);
    atomicAdd(&ksumS[mp + 1], ksp1);
    #pragma unroll
    for (int i = 0; i < 2; i++)
        #pragma unroll
        for (int j = 0; j < 2; j++)
            #pragma unroll
            for (int r = 0; r < 4; r++)
                kvT[wc * 32 + j * 16 + lm][wr * 32 + i * 16 + q * 4 + r] =
                    (bf16)akv[i][j][r];
    __syncthreads();

    const int prow = tid >> 2;
    const int pseg = (tid & 3) * 16;
    for (int t8 = 0; t8 < 9; t8++) {
        const int s0 = t8 * 64;
        const int gs = s0 + prow;
        if (gs < 513) {
            *(bf16x8*)(&pqS[prow][pseg])     = *(const bf16x8*)(qkv + rbQ + (long)gs * 1536 + pseg);
            *(bf16x8*)(&pqS[prow][pseg + 8]) = *(const bf16x8*)(qkv + rbQ + (long)gs * 1536 + pseg + 8);
        } else {
            bf16x8 z;
            for (int r = 0; r < 8; r++) z[r] = (bf16)0.f;
            *(bf16x8*)(&pqS[prow][pseg])     = z;
            *(bf16x8*)(&pqS[prow][pseg + 8]) = z;
        }
        __syncthreads();
        {
            const int s = tid >> 2, mb = (tid & 3) * 16;
            float dp = 0.f;
            #pragma unroll
            for (int m2 = 0; m2 < 16; m2++)
                dp += (float)pqS[s][mb + m2] * ksumS[mb + m2];
            dp += __shfl_xor(dp, 1);
            dp += __shfl_xor(dp, 2);
            if ((tid & 3) == 0) denS[s] = dp;
        }
        __syncthreads();
        f32x4 an[4];
        for (int j = 0; j < 4; j++)
            for (int r = 0; r < 4; r++) an[j][r] = 0.f;
        #pragma unroll
        for (int ks = 0; ks < 2; ks++) {
            bf16x8 a = *(const bf16x8*)(&pqS[wave * 16 + lm][ks * 32 + q * 8]);
            #pragma unroll
            for (int j = 0; j < 4; j++) {
                bf16x8 bb = *(const bf16x8*)(&kvT[j * 16 + lm][ks * 32 + q * 8]);
                an[j] = __builtin_amdgcn_mfma_f32_16x16x32_bf16(a, bb, an[j], 0, 0, 0);
            }
        }
        #pragma unroll
        for (int j = 0; j < 4; j++) {
            #pragma unroll
            for (int r = 0; r < 4; r++) {
                const int sl  = wave * 16 + q * 4 + r;
                const int gs2 = s0 + sl;
                if (gs2 < 513) {
                    const int d = j * 16 + lm;
                    qkv[rbQ + (long)gs2 * 1536 + d] = (bf16)(an[j][r] / denS[sl]);
                }
            }
        }
        __syncthreads();
    }
}

__global__ __launch_bounds__(256) void ln_res(
    const bf16* __restrict__ y, int ldy, const float* __restrict__ sc,
    const float* __restrict__ bi, bf16* __restrict__ xb)
{
    const int row  = blockIdx.x * 4 + (threadIdx.x >> 6);
    const int lane = threadIdx.x & 63;
    const bf16* yr = y  + (long)row * ldy + lane * 8;
    bf16*       xr = xb + (long)row * 512 + lane * 8;
    bf16x8 yv = *(const bf16x8*)yr;
    bf16x8 xv = *(const bf16x8*)xr;
    float v[8];
    float sum = 0.f;
    #pragma unroll
    for (int i = 0; i < 8; i++) { v[i] = (float)yv[i] + (float)xv[i]; sum += v[i]; }
    #pragma unroll
    for (int o = 32; o; o >>= 1) sum += __shfl_xor(sum, o);
    const float mean = sum * (1.f / 512.f);
    float vs = 0.f;
    #pragma unroll
    for (int i = 0; i < 8; i++) { float dd = v[i] - mean; vs += dd * dd; }
    #pragma unroll
    for (int o = 32; o; o >>= 1) vs += __shfl_xor(vs, o);
    const float rstd = rsqrtf(vs * (1.f / 512.f) + 1e-6f);
    bf16x8 ov;
    #pragma unroll
    for (int i = 0; i < 8; i++)
        ov[i] = (bf16)((v[i] - mean) * rstd * sc[lane * 8 + i] + bi[lane * 8 + i]);
    *(bf16x8*)xr = ov;
}

__global__ __launch_bounds__(256) void final_head(
    const bf16* __restrict__ xb, const float* __restrict__ Wqp,
    const float* __restrict__ bqp, float* __restrict__ out)
{
    const int b = blockIdx.x;
    const bf16* xr = xb + (long)b * 513 * 512;
    for (int i = threadIdx.x; i < 512; i += 256) out[b * 512 + i] = (float)xr[i];
    const int a = threadIdx.x & 15, g = threadIdx.x >> 4;
    float p = 0.f;
    for (int k = g * 32; k < g * 32 + 32; k++)
        p += (float)xr[k] * Wqp[k * 16 + a];
    __shared__ float red[256];
    red[threadIdx.x] = p;
    __syncthreads();
    if (threadIdx.x < 16) {
        float s = bqp[a];
        for (int g2 = 0; g2 < 16; g2++) s += red[g2 * 16 + a];
        out[64 * 512 + b * 16 + a] = s;
    }
}

extern "C" void kernel_launch(void* const* d_in, const int* in_sizes, int n_in,
                              void* d_out, int out_size, void* d_ws, size_t ws_size,
                              hipStream_t stream)
{
    (void)in_sizes; (void)n_in; (void)out_size; (void)ws_size;
    const float* hs    = (const float*)d_in[0];
    const float* ins   = (const float*)d_in[1];
    const int*   resets= (const int*)d_in[2];
    const float* W_emb = (const float*)d_in[3];
    const float* b_emb = (const float*)d_in[4];
    const float* Wq    = (const float*)d_in[5];
    const float* bq    = (const float*)d_in[6];
    const float* Wk    = (const float*)d_in[7];
    const float* bk    = (const float*)d_in[8];
    const float* Wv    = (const float*)d_in[9];
    const float* bv    = (const float*)d_in[10];
    const float* Wo    = (const float*)d_in[11];
    const float* bo    = (const float*)d_in[12];
    const float* ln1s  = (const float*)d_in[13];
    const float* ln1b  = (const float*)d_in[14];
    const float* ln2s  = (const float*)d_in[15];
    const float* ln2b  = (const float*)d_in[16];
    const float* W1    = (const float*)d_in[17];
    const float* b1    = (const float*)d_in[18];
    const float* W2    = (const float*)d_in[19];
    const float* b2    = (const float*)d_in[20];
    const float* Wqp   = (const float*)d_in[21];
    const float* bqp   = (const float*)d_in[22];
    float* out = (float*)d_out;
    char* ws  = (char*)d_ws;

    // ---- workspace layout (bytes), peak ~149.30 MB ----
    // xb   [32832][512]  bf16   @ 0            (33,619,968)
    // qkv  [32832][1536] bf16   @ 33,619,968   (100,859,904)
    //   f  [16416][2048] bf16   @ qkv+0        (67,239,936)   (FFN, qkv dead)
    //   y2 [32832][512]  bf16   @ qkv+67,239,936 (33,619,968) (exact fit)
    // WembT               @ 134,479,872  (131,072)  -> reused as bqkv_all after embed
    // LW                  @ 134,610,944: WqkvT(1,572,864) WoT(524,288)
    //                       W1T(2,097,152) W2T(2,097,152)
    // insb                @ 140,908,544  (8,388,608)  -> end 149,297,152
    bf16* xb   = (bf16*)(ws);
    bf16* qkv  = (bf16*)(ws + 33619968);
    bf16* f    = qkv;
    bf16* y2   = (bf16*)(ws + 33619968 + 67239936);
    bf16* WembT= (bf16*)(ws + 134479872);
    float* bqkv_all = (float*)(ws + 134479872);   // 24KB, reuses WembT after embed
    char* LW   = ws + 134610944;
    bf16* WqkvT= (bf16*)(LW + 0);
    bf16* WoT  = (bf16*)(LW + 1572864);
    bf16* W1T  = (bf16*)(LW + 2097152);
    bf16* W2T  = (bf16*)(LW + 4194304);
    bf16* insb = (bf16*)(ws + 140908544);

    cvt_bf16<<<4096, 256, 0, stream>>>(ins, insb, 4194304);
    transpose_f32<<<dim3(16, 4), 256, 0, stream>>>(W_emb, WembT, 128, 512, 0);
    build_x0<<<64, 256, 0, stream>>>(hs, resets, xb);
    gemm128<1, 0><<<dim3(4, 256), 256, 0, stream>>>(
        insb, WembT, b_emb, xb, 32768, 512, 128, 128, 512);
    // WembT dead from here; bqkv_all takes the region
    concat_all<<<24, 256, 0, stream>>>(bq, bk, bv, bqkv_all);

    for (int l = 0; l < 4; l++) {
        const long o512  = (long)l * 262144;
        const long o2048 = (long)l * 1048576;
        prep_qkvo<<<dim3(16, 16, 4), 256, 0, stream>>>(Wq, Wk, Wv, Wo, WqkvT, WoT, o512);
        prep_ffn<<<dim3(64, 16, 2), 256, 0, stream>>>(W1, W2, W1T, W2T, o2048);

        // fused QKV: qkv[row][1536], relu+eps on cols<1024 (q,k), none on v
        gemm128<0, 3><<<dim3(12, 257), 256, 0, stream>>>(
            xb, WqkvT, bqkv_all + l * 1536, qkv, 32832, 1536, 512, 512, 1536);
        favor_mfma<<<512, 256, 0, stream>>>(qkv);
        // O-proj: A = ao (pq slice of qkv, lda 1536), out y -> pk slice (ldc 1536)
        gemm128<0, 0><<<dim3(4, 257), 256, 0, stream>>>(
            qkv, WoT, bo + l * 512, qkv + 512, 32832, 512, 512, 1536, 1536);
        ln_res<<<8208, 256, 0, stream>>>(qkv + 512, 1536, ln1s + l * 512, ln1b + l * 512, xb);

        // FFN in two 16416-row chunks; f + y2 alias exactly inside qkv region
        for (int c = 0; c < 2; c++) {
            const long r0 = (long)c * 16416;
            gemm128<0, 1><<<dim3(16, 129), 256, 0, stream>>>(
                xb + r0 * 512, W1T, b1 + l * 2048, f, 16416, 2048, 512, 512, 2048);
            gemm128<0, 0><<<dim3(4, 129), 256, 0, stream>>>(
                f, W2T, b2 + l * 512, y2 + r0 * 512, 16416, 512, 2048, 2048, 512);
        }
        ln_res<<<8208, 256, 0, stream>>>(y2, 512, ln2s + l * 512, ln2b + l * 512, xb);
    }

    final_head<<<64, 256, 0, stream>>>(xb, Wqp, bqp, out);
}

// Round 9
// 1814.738 us; speedup vs baseline: 1.4397x; 1.0423x over previous
//
#include <hip/hip_runtime.h>

typedef __bf16 bf16;
typedef __bf16 bf16x8 __attribute__((ext_vector_type(8)));
typedef float  f32x4  __attribute__((ext_vector_type(4)));

// B=64, S=512, OBS=128, D=512, H=8, F=2048, L=4, A=16; rows M = B*513 = 32832
// R24 = R23 (best, 1891us) + SCHED template split in gemm128:
//   SCHED=0: R23 single-buffer 2-barrier loop (16KB LDS) -- used where block
//            demand > occupancy capacity (QKV 12/CU, FFN-up 8/CU): TLP rules.
//   SCHED=1: R20's proven double-buffer single-barrier 2-phase loop (32KB
//            LDS) -- used ONLY for grid-starved gemms (embed 4/CU, O-proj
//            4/CU, FFN-down 2/CU) where demand <= 5-block LDS cap: zero
//            occupancy cost, pure latency overlap.
// R23 forensics: SQ_LDS_BANK_CONFLICT = 8.0 per global_load_lds exactly ->
// conflicts are the DMA deposit (structural), ds_reads already conflict-free;
// read swizzle kept (neutral, proven).  Batched preps kept.

__device__ __forceinline__ void cp16(const bf16* g, bf16* l)
{
    __builtin_amdgcn_global_load_lds(
        (const __attribute__((address_space(1))) void*)g,
        (__attribute__((address_space(3))) void*)l,
        16, 0, 0);
}

__global__ __launch_bounds__(256) void cvt_bf16(
    const float* __restrict__ src, bf16* __restrict__ dst, int n)
{
    for (int i = blockIdx.x * 256 + threadIdx.x; i < n; i += gridDim.x * 256)
        dst[i] = (bf16)src[i];
}

__global__ __launch_bounds__(256) void transpose_f32(
    const float* __restrict__ W, bf16* __restrict__ WT, int K, int N, long elemOff)
{
    __shared__ bf16 tile[32][33];
    const int bn = blockIdx.x * 32;
    const int bk = blockIdx.y * 32;
    const int tx = threadIdx.x & 31, ty = threadIdx.x >> 5;
    for (int r = 0; r < 32; r += 8)
        tile[ty + r][tx] = (bf16)W[elemOff + (long)(bk + ty + r) * N + (bn + tx)];
    __syncthreads();
    for (int r = 0; r < 32; r += 8)
        WT[(long)(bn + ty + r) * K + (bk + tx)] = tile[tx][ty + r];
}

// z=0..3 -> transpose 512x512 slice of {Wq,Wk,Wv,Wo}[layer] into
// {WqkvT+0, WqkvT+256K, WqkvT+512K, WoT}.
__global__ __launch_bounds__(256) void prep_qkvo(
    const float* __restrict__ Wq, const float* __restrict__ Wk,
    const float* __restrict__ Wv, const float* __restrict__ Wo,
    bf16* __restrict__ WqkvT, bf16* __restrict__ WoT, long elemOff)
{
    __shared__ bf16 tile[32][33];
    const int z = blockIdx.z;
    const float* W = (z == 0) ? Wq : (z == 1) ? Wk : (z == 2) ? Wv : Wo;
    bf16* WT = (z < 3) ? (WqkvT + (long)z * 262144) : WoT;
    const int bn = blockIdx.x * 32;
    const int bk = blockIdx.y * 32;
    const int tx = threadIdx.x & 31, ty = threadIdx.x >> 5;
    for (int r = 0; r < 32; r += 8)
        tile[ty + r][tx] = (bf16)W[elemOff + (long)(bk + ty + r) * 512 + (bn + tx)];
    __syncthreads();
    for (int r = 0; r < 32; r += 8)
        WT[(long)(bn + ty + r) * 512 + (bk + tx)] = tile[tx][ty + r];
}

// z=0: W1 [512][2048] -> W1T [2048][512];  z=1: W2 [2048][512] -> W2T [512][2048]
__global__ __launch_bounds__(256) void prep_ffn(
    const float* __restrict__ W1, const float* __restrict__ W2,
    bf16* __restrict__ W1T, bf16* __restrict__ W2T, long elemOff)
{
    __shared__ bf16 tile[32][33];
    const int z = blockIdx.z;
    const float* W = z ? W2 : W1;
    bf16* WT = z ? W2T : W1T;
    const int N = z ? 512 : 2048;
    const int K = z ? 2048 : 512;
    const int bn = (z ? blockIdx.y : blockIdx.x) * 32;
    const int bk = (z ? blockIdx.x : blockIdx.y) * 32;
    const int tx = threadIdx.x & 31, ty = threadIdx.x >> 5;
    for (int r = 0; r < 32; r += 8)
        tile[ty + r][tx] = (bf16)W[elemOff + (long)(bk + ty + r) * N + (bn + tx)];
    __syncthreads();
    for (int r = 0; r < 32; r += 8)
        WT[(long)(bn + ty + r) * K + (bk + tx)] = tile[tx][ty + r];
}

// all 4 layers' {bq,bk,bv} -> bqkv_all[l][1536] in one launch (24 blocks)
__global__ __launch_bounds__(256) void concat_all(
    const float* __restrict__ bq, const float* __restrict__ bk,
    const float* __restrict__ bv, float* __restrict__ dst)
{
    const int i = blockIdx.x * 256 + threadIdx.x;   // 0..6143
    if (i >= 6144) return;
    const int lay = i / 1536;
    const int rem = i - lay * 1536;
    float v;
    if (rem < 512)        v = bq[lay * 512 + rem];
    else if (rem < 1024)  v = bk[lay * 512 + rem - 512];
    else                  v = bv[lay * 512 + rem - 1024];
    dst[lay * 1536 + rem] = v;
}

__global__ __launch_bounds__(256) void build_x0(
    const float* __restrict__ hs, const int* __restrict__ resets,
    bf16* __restrict__ xb)
{
    const int b = blockIdx.x;
    const bool rz = (resets[b] != 0);
    const long base = (long)b * 513 * 512;
    for (int d = threadIdx.x; d < 512; d += 256)
        xb[base + d] = rz ? (bf16)0.f : (bf16)hs[b * 512 + d];
}

// GEMM: C[M,N] = A[M,K] @ BT[N,K]^T + bias(fp32).  128x128 tile, BK=32,
// 4 waves x (4x4) 16x16x32 MFMA, global_load_lds(16B) direct-to-LDS staging.
// LDS [128][32] linear dest; T2 XOR swizzle via pre-swizzled GLOBAL source
// (ksw) + swizzled read seg (qx).  N%128==0; M tail via overlap clamp.
// A row stride lda, C row stride ldc.  Bijective XCD swizzle.
// ROWMAP==1: row += row/512 + 1.  ACT: 0=none 1=relu 2=relu+eps 3=relu+eps iff col<1024.
// SCHED: 0 = single-buffer 2-barrier (R23); 1 = dbuf single-barrier 2-phase (R20).
template<int ROWMAP, int ACT, int SCHED>
__global__ __launch_bounds__(256) void gemm128(
    const bf16* __restrict__ A, const bf16* __restrict__ BT,
    const float* __restrict__ bias, bf16* __restrict__ outB,
    int M, int N, int K, int lda, int ldc)
{
    __shared__ bf16 As[(SCHED + 1) * 128 * 32];
    __shared__ bf16 Bs[(SCHED + 1) * 128 * 32];
    const int tid  = threadIdx.x;
    const int wave = tid >> 6;
    const int lane = tid & 63;
    const int q    = lane >> 4;
    const int lm   = lane & 15;
    const int wr   = wave >> 1, wc = wave & 1;

    // bijective XCD swizzle (m204): orig%8 = XCD slot -> contiguous partition
    int flat;
    {
        const int nwg  = gridDim.x * gridDim.y;
        const int orig = blockIdx.y * gridDim.x + blockIdx.x;
        const int qq = nwg >> 3, rr = nwg & 7;
        const int xcd = orig & 7, idx = orig >> 3;
        flat = (xcd < rr ? xcd * (qq + 1) : rr * (qq + 1) + (xcd - rr) * qq) + idx;
    }
    const int bx = flat % gridDim.x;
    const int by = flat / gridDim.x;
    int m0 = by * 128;
    if (m0 > M - 128) m0 = M - 128;            // tail overlap clamp
    const int n0 = bx * 128;

    // staging geometry: wave w issue i deposits rows w*32+i*16+(l>>2) at
    // linear LDS slot l (elem row*32 + (l&3)*8).  T2: lane fetches k-seg
    // (l&3)^((l>>2)&3) so physical (row,kp) holds logical kp^(row&3).
    const int r0  = wave * 32 + (lane >> 2);
    const int ksw = ((lane & 3) ^ ((lane >> 2) & 3)) * 8;
    const bf16* Ag0 = A  + (long)(m0 + r0) * lda + ksw;
    const bf16* Ag1 = A  + (long)(m0 + r0 + 16) * lda + ksw;
    const bf16* Bg0 = BT + (long)(n0 + r0) * K + ksw;
    const bf16* Bg1 = BT + (long)(n0 + r0 + 16) * K + ksw;

    // read-side swizzle: logical seg q lives at physical q^(row&3), row&3 = lm&3
    const int qx = (q ^ (lm & 3)) * 8;

    f32x4 acc[4][4];
    for (int i = 0; i < 4; i++) for (int j = 0; j < 4; j++)
        for (int r = 0; r < 4; r++) acc[i][j][r] = 0.f;

    if constexpr (SCHED == 0) {
        bf16* Al0 = As + wave * 1024;
        bf16* Al1 = As + wave * 1024 + 512;
        bf16* Bl0 = Bs + wave * 1024;
        bf16* Bl1 = Bs + wave * 1024 + 512;
        for (int k0 = 0; k0 < K; k0 += 32) {
            cp16(Ag0 + k0, Al0);
            cp16(Ag1 + k0, Al1);
            cp16(Bg0 + k0, Bl0);
            cp16(Bg1 + k0, Bl1);
            __syncthreads();                   // drains vmcnt -> DMA landed
            bf16x8 af[4], bfr[4];
            #pragma unroll
            for (int i = 0; i < 4; i++)
                af[i] = *(const bf16x8*)(As + (wr * 64 + i * 16 + lm) * 32 + qx);
            #pragma unroll
            for (int j = 0; j < 4; j++)
                bfr[j] = *(const bf16x8*)(Bs + (wc * 64 + j * 16 + lm) * 32 + qx);
            #pragma unroll
            for (int i = 0; i < 4; i++)
                #pragma unroll
                for (int j = 0; j < 4; j++)
                    acc[i][j] = __builtin_amdgcn_mfma_f32_16x16x32_bf16(
                        af[i], bfr[j], acc[i][j], 0, 0, 0);
            __syncthreads();                   // LDS safe for next DMA
        }
    } else {
        // R20 2-phase: STAGE(t+1) first, compute buf[cur], one barrier/iter.
        const int lb = wave * 1024;
        const int NT = K >> 5;
#define STAGE24(kt, buf)                                       \
        do {                                                   \
            const int _k0 = (kt) * 32;                         \
            cp16(Ag0 + _k0, &As[(buf) * 4096 + lb]);           \
            cp16(Ag1 + _k0, &As[(buf) * 4096 + lb + 512]);     \
            cp16(Bg0 + _k0, &Bs[(buf) * 4096 + lb]);           \
            cp16(Bg1 + _k0, &Bs[(buf) * 4096 + lb + 512]);     \
        } while (0)
        STAGE24(0, 0);
        asm volatile("s_waitcnt vmcnt(0)" ::: "memory");
        __builtin_amdgcn_s_barrier();
        int cur = 0;
        for (int t = 0; t < NT; ++t) {
            if (t + 1 < NT) STAGE24(t + 1, cur ^ 1);   // next-tile DMA FIRST
            bf16x8 af[4], bfr[4];
            #pragma unroll
            for (int i = 0; i < 4; i++)
                af[i] = *(const bf16x8*)(&As[cur * 4096 + (wr * 64 + i * 16 + lm) * 32 + qx]);
            #pragma unroll
            for (int j = 0; j < 4; j++)
                bfr[j] = *(const bf16x8*)(&Bs[cur * 4096 + (wc * 64 + j * 16 + lm) * 32 + qx]);
            #pragma unroll
            for (int i = 0; i < 4; i++)
                #pragma unroll
                for (int j = 0; j < 4; j++)
                    acc[i][j] = __builtin_amdgcn_mfma_f32_16x16x32_bf16(
                        af[i], bfr[j], acc[i][j], 0, 0, 0);
            asm volatile("s_waitcnt vmcnt(0)" ::: "memory");
            __builtin_amdgcn_s_barrier();
            cur ^= 1;
        }
#undef STAGE24
    }

    // C/D: col = lane&15, row = (lane>>4)*4 + r  [session-verified]
    #pragma unroll
    for (int j = 0; j < 4; j++) {
        const int col = n0 + wc * 64 + j * 16 + lm;
        const float bv = bias[col];
        #pragma unroll
        for (int i = 0; i < 4; i++) {
            #pragma unroll
            for (int r = 0; r < 4; r++) {
                int row = m0 + wr * 64 + i * 16 + q * 4 + r;
                float vv = acc[i][j][r] + bv;
                if (ACT == 1) vv = fmaxf(vv, 0.f);
                if (ACT == 2) vv = fmaxf(vv, 0.f) + 1e-3f;
                if (ACT == 3 && col < 1024) vv = fmaxf(vv, 0.f) + 1e-3f;
                if (ROWMAP == 1) row = row + (row >> 9) + 1;
                outB[(long)row * ldc + col] = (bf16)vv;
            }
        }
    }
}

// FAVOR+ attention, full MFMA.  Reads pq/pk/vv as column slices {0,512,1024}
// of the strided qkv[row][1536] buffer; writes ao back into the pq slice
// (per-(b,h) alias safe: each t8 tile's pq rows are staged before overwrite).
#define FP 72
__global__ __launch_bounds__(256) void favor_mfma(bf16* qkv)
{
    const int bh = blockIdx.x;
    const int b = bh >> 3, h = bh & 7;
    const long rbQ = (long)b * 513 * 1536 + h * 64;
    const long rbK = rbQ + 512;
    const long rbV = rbQ + 1024;

    __shared__ bf16 pkT[64][FP];
    __shared__ bf16 vT [64][FP];
    __shared__ bf16 kvT[64][FP];
    __shared__ bf16 pqS[64][FP];
    __shared__ float ksumS[64];
    __shared__ float denS[64];

    const int tid  = threadIdx.x;
    const int wave = tid >> 6;
    const int lane = tid & 63;
    const int q    = lane >> 4;
    const int lm   = lane & 15;
    const int wr   = wave >> 1, wc = wave & 1;
    const int mp   = (tid & 31) * 2;
    const int sr   = tid >> 5;

    if (tid < 64) ksumS[tid] = 0.f;
    float ksp0 = 0.f, ksp1 = 0.f;

    f32x4 akv[2][2];
    for (int i = 0; i < 2; i++) for (int j = 0; j < 2; j++)
        for (int r = 0; r < 4; r++) akv[i][j][r] = 0.f;

    for (int t8 = 0; t8 < 9; t8++) {
        const int s0 = t8 * 64;
        #pragma unroll
        for (int i = 0; i < 8; i++) {
            const int s  = sr + i * 8;
            const int gs = s0 + s;
            unsigned pkw = 0, vw = 0;
            if (gs < 513) {
                pkw = *(const unsigned*)(qkv + rbK + (long)gs * 1536 + mp);
                vw  = *(const unsigned*)(qkv + rbV + (long)gs * 1536 + mp);
            }
            union { unsigned u; bf16 hh[2]; } pu, vu;
            pu.u = pkw; vu.u = vw;
            pkT[mp][s]     = pu.hh[0];
            pkT[mp + 1][s] = pu.hh[1];
            vT[mp][s]      = vu.hh[0];
            vT[mp + 1][s]  = vu.hh[1];
            ksp0 += (float)pu.hh[0];
            ksp1 += (float)pu.hh[1];
        }
        __syncthreads();
        #pragma unroll
        for (int ks = 0; ks < 2; ks++) {
            bf16x8 a0 = *(const bf16x8*)(&pkT[wr * 32 + lm     ][ks * 32 + q * 8]);
            bf16x8 a1 = *(const bf16x8*)(&pkT[wr * 32 + 16 + lm][ks * 32 + q * 8]);
            bf16x8 b0 = *(const bf16x8*)(&vT [wc * 32 + lm     ][ks * 32 + q * 8]);
            bf16x8 b1 = *(const bf16x8*)(&vT [wc * 32 + 16 + lm][ks * 32 + q * 8]);
            akv[0][0] = __builtin_amdgcn_mfma_f32_16x16x32_bf16(a0, b0, akv[0][0], 0, 0, 0);
            akv[0][1] = __builtin_amdgcn_mfma_f32_16x16x32_bf16(a0, b1, akv[0][1], 0, 0, 0);
            akv[1][0] = __builtin_amdgcn_mfma_f32_16x16x32_bf16(a1, b0, akv[1][0], 0, 0, 0);
            akv[1][1] = __builtin_amdgcn_mfma_f32_16x16x32_bf16(a1, b1, akv[1][1], 0, 0, 0);
        }
        __syncthreads();
    }
    atomicAdd(&ksumS[mp],     ksp0);
    atomicAdd(&ksumS[mp + 1], ksp1);
    #pragma unroll
    for (int i = 0; i < 2; i++)
        #pragma unroll
        for (int j = 0; j < 2; j++)
            #pragma unroll
            for (int r = 0; r < 4; r++)
                kvT[wc * 32 + j * 16 + lm][wr * 32 + i * 16 + q * 4 + r] =
                    (bf16)akv[i][j][r];
    __syncthreads();

    const int prow = tid >> 2;
    const int pseg = (tid & 3) * 16;
    for (int t8 = 0; t8 < 9; t8++) {
        const int s0 = t8 * 64;
        const int gs = s0 + prow;
        if (gs < 513) {
            *(bf16x8*)(&pqS[prow][pseg])     = *(const bf16x8*)(qkv + rbQ + (long)gs * 1536 + pseg);
            *(bf16x8*)(&pqS[prow][pseg + 8]) = *(const bf16x8*)(qkv + rbQ + (long)gs * 1536 + pseg + 8);
        } else {
            bf16x8 z;
            for (int r = 0; r < 8; r++) z[r] = (bf16)0.f;
            *(bf16x8*)(&pqS[prow][pseg])     = z;
            *(bf16x8*)(&pqS[prow][pseg + 8]) = z;
        }
        __syncthreads();
        {
            const int s = tid >> 2, mb = (tid & 3) * 16;
            float dp = 0.f;
            #pragma unroll
            for (int m2 = 0; m2 < 16; m2++)
                dp += (float)pqS[s][mb + m2] * ksumS[mb + m2];
            dp += __shfl_xor(dp, 1);
            dp += __shfl_xor(dp, 2);
            if ((tid & 3) == 0) denS[s] = dp;
        }
        __syncthreads();
        f32x4 an[4];
        for (int j = 0; j < 4; j++)
            for (int r = 0; r < 4; r++) an[j][r] = 0.f;
        #pragma unroll
        for (int ks = 0; ks < 2; ks++) {
            bf16x8 a = *(const bf16x8*)(&pqS[wave * 16 + lm][ks * 32 + q * 8]);
            #pragma unroll
            for (int j = 0; j < 4; j++) {
                bf16x8 bb = *(const bf16x8*)(&kvT[j * 16 + lm][ks * 32 + q * 8]);
                an[j] = __builtin_amdgcn_mfma_f32_16x16x32_bf16(a, bb, an[j], 0, 0, 0);
            }
        }
        #pragma unroll
        for (int j = 0; j < 4; j++) {
            #pragma unroll
            for (int r = 0; r < 4; r++) {
                const int sl  = wave * 16 + q * 4 + r;
                const int gs2 = s0 + sl;
                if (gs2 < 513) {
                    const int d = j * 16 + lm;
                    qkv[rbQ + (long)gs2 * 1536 + d] = (bf16)(an[j][r] / denS[sl]);
                }
            }
        }
        __syncthreads();
    }
}

__global__ __launch_bounds__(256) void ln_res(
    const bf16* __restrict__ y, int ldy, const float* __restrict__ sc,
    const float* __restrict__ bi, bf16* __restrict__ xb)
{
    const int row  = blockIdx.x * 4 + (threadIdx.x >> 6);
    const int lane = threadIdx.x & 63;
    const bf16* yr = y  + (long)row * ldy + lane * 8;
    bf16*       xr = xb + (long)row * 512 + lane * 8;
    bf16x8 yv = *(const bf16x8*)yr;
    bf16x8 xv = *(const bf16x8*)xr;
    float v[8];
    float sum = 0.f;
    #pragma unroll
    for (int i = 0; i < 8; i++) { v[i] = (float)yv[i] + (float)xv[i]; sum += v[i]; }
    #pragma unroll
    for (int o = 32; o; o >>= 1) sum += __shfl_xor(sum, o);
    const float mean = sum * (1.f / 512.f);
    float vs = 0.f;
    #pragma unroll
    for (int i = 0; i < 8; i++) { float dd = v[i] - mean; vs += dd * dd; }
    #pragma unroll
    for (int o = 32; o; o >>= 1) vs += __shfl_xor(vs, o);
    const float rstd = rsqrtf(vs * (1.f / 512.f) + 1e-6f);
    bf16x8 ov;
    #pragma unroll
    for (int i = 0; i < 8; i++)
        ov[i] = (bf16)((v[i] - mean) * rstd * sc[lane * 8 + i] + bi[lane * 8 + i]);
    *(bf16x8*)xr = ov;
}

__global__ __launch_bounds__(256) void final_head(
    const bf16* __restrict__ xb, const float* __restrict__ Wqp,
    const float* __restrict__ bqp, float* __restrict__ out)
{
    const int b = blockIdx.x;
    const bf16* xr = xb + (long)b * 513 * 512;
    for (int i = threadIdx.x; i < 512; i += 256) out[b * 512 + i] = (float)xr[i];
    const int a = threadIdx.x & 15, g = threadIdx.x >> 4;
    float p = 0.f;
    for (int k = g * 32; k < g * 32 + 32; k++)
        p += (float)xr[k] * Wqp[k * 16 + a];
    __shared__ float red[256];
    red[threadIdx.x] = p;
    __syncthreads();
    if (threadIdx.x < 16) {
        float s = bqp[a];
        for (int g2 = 0; g2 < 16; g2++) s += red[g2 * 16 + a];
        out[64 * 512 + b * 16 + a] = s;
    }
}

extern "C" void kernel_launch(void* const* d_in, const int* in_sizes, int n_in,
                              void* d_out, int out_size, void* d_ws, size_t ws_size,
                              hipStream_t stream)
{
    (void)in_sizes; (void)n_in; (void)out_size; (void)ws_size;
    const float* hs    = (const float*)d_in[0];
    const float* ins   = (const float*)d_in[1];
    const int*   resets= (const int*)d_in[2];
    const float* W_emb = (const float*)d_in[3];
    const float* b_emb = (const float*)d_in[4];
    const float* Wq    = (const float*)d_in[5];
    const float* bq    = (const float*)d_in[6];
    const float* Wk    = (const float*)d_in[7];
    const float* bk    = (const float*)d_in[8];
    const float* Wv    = (const float*)d_in[9];
    const float* bv    = (const float*)d_in[10];
    const float* Wo    = (const float*)d_in[11];
    const float* bo    = (const float*)d_in[12];
    const float* ln1s  = (const float*)d_in[13];
    const float* ln1b  = (const float*)d_in[14];
    const float* ln2s  = (const float*)d_in[15];
    const float* ln2b  = (const float*)d_in[16];
    const float* W1    = (const float*)d_in[17];
    const float* b1    = (const float*)d_in[18];
    const float* W2    = (const float*)d_in[19];
    const float* b2    = (const float*)d_in[20];
    const float* Wqp   = (const float*)d_in[21];
    const float* bqp   = (const float*)d_in[22];
    float* out = (float*)d_out;
    char* ws  = (char*)d_ws;

    // ---- workspace layout (bytes), peak ~149.30 MB ----
    // xb   [32832][512]  bf16   @ 0            (33,619,968)
    // qkv  [32832][1536] bf16   @ 33,619,968   (100,859,904)
    //   f  [16416][2048] bf16   @ qkv+0        (67,239,936)   (FFN, qkv dead)
    //   y2 [32832][512]  bf16   @ qkv+67,239,936 (33,619,968) (exact fit)
    // WembT               @ 134,479,872  (131,072)  -> reused as bqkv_all after embed
    // LW                  @ 134,610,944: WqkvT(1,572,864) WoT(524,288)
    //                       W1T(2,097,152) W2T(2,097,152)
    // insb                @ 140,908,544  (8,388,608)  -> end 149,297,152
    bf16* xb   = (bf16*)(ws);
    bf16* qkv  = (bf16*)(ws + 33619968);
    bf16* f    = qkv;
    bf16* y2   = (bf16*)(ws + 33619968 + 67239936);
    bf16* WembT= (bf16*)(ws + 134479872);
    float* bqkv_all = (float*)(ws + 134479872);   // 24KB, reuses WembT after embed
    char* LW   = ws + 134610944;
    bf16* WqkvT= (bf16*)(LW + 0);
    bf16* WoT  = (bf16*)(LW + 1572864);
    bf16* W1T  = (bf16*)(LW + 2097152);
    bf16* W2T  = (bf16*)(LW + 4194304);
    bf16* insb = (bf16*)(ws + 140908544);

    cvt_bf16<<<4096, 256, 0, stream>>>(ins, insb, 4194304);
    transpose_f32<<<dim3(16, 4), 256, 0, stream>>>(W_emb, WembT, 128, 512, 0);
    build_x0<<<64, 256, 0, stream>>>(hs, resets, xb);
    gemm128<1, 0, 1><<<dim3(4, 256), 256, 0, stream>>>(
        insb, WembT, b_emb, xb, 32768, 512, 128, 128, 512);
    // WembT dead from here; bqkv_all takes the region
    concat_all<<<24, 256, 0, stream>>>(bq, bk, bv, bqkv_all);

    for (int l = 0; l < 4; l++) {
        const long o512  = (long)l * 262144;
        const long o2048 = (long)l * 1048576;
        prep_qkvo<<<dim3(16, 16, 4), 256, 0, stream>>>(Wq, Wk, Wv, Wo, WqkvT, WoT, o512);
        prep_ffn<<<dim3(64, 16, 2), 256, 0, stream>>>(W1, W2, W1T, W2T, o2048);

        // fused QKV (demand 12 blocks/CU -> SCHED=0 keeps TLP)
        gemm128<0, 3, 0><<<dim3(12, 257), 256, 0, stream>>>(
            xb, WqkvT, bqkv_all + l * 1536, qkv, 32832, 1536, 512, 512, 1536);
        favor_mfma<<<512, 256, 0, stream>>>(qkv);
        // O-proj (demand 4/CU <= 5-block cap -> SCHED=1 pipeline, free)
        gemm128<0, 0, 1><<<dim3(4, 257), 256, 0, stream>>>(
            qkv, WoT, bo + l * 512, qkv + 512, 32832, 512, 512, 1536, 1536);
        ln_res<<<8208, 256, 0, stream>>>(qkv + 512, 1536, ln1s + l * 512, ln1b + l * 512, xb);

        // FFN in two 16416-row chunks; f + y2 alias exactly inside qkv region
        for (int c = 0; c < 2; c++) {
            const long r0 = (long)c * 16416;
            // up: demand 8/CU -> SCHED=0
            gemm128<0, 1, 0><<<dim3(16, 129), 256, 0, stream>>>(
                xb + r0 * 512, W1T, b1 + l * 2048, f, 16416, 2048, 512, 512, 2048);
            // down: demand 2/CU, K=2048 (64 iters) -> SCHED=1 pipeline
            gemm128<0, 0, 1><<<dim3(4, 129), 256, 0, stream>>>(
                f, W2T, b2 + l * 512, y2 + r0 * 512, 16416, 512, 2048, 2048, 512);
        }
        ln_res<<<8208, 256, 0, stream>>>(y2, 512, ln2s + l * 512, ln2b + l * 512, xb);
    }

    final_head<<<64, 256, 0, stream>>>(xb, Wqp, bqp, out);
}

// Round 10
// 1773.884 us; speedup vs baseline: 1.4729x; 1.0230x over previous
//
#include <hip/hip_runtime.h>

typedef __bf16 bf16;
typedef __bf16 bf16x8 __attribute__((ext_vector_type(8)));
typedef float  f32x4  __attribute__((ext_vector_type(4)));

// B=64, S=512, OBS=128, D=512, H=8, F=2048, L=4, A=16; rows M = B*513 = 32832
// R25 = R24 (best, 1814us) + vectorized favor_mfma pass-1 staging:
//   - pk/v loads 4B -> 16B per lane (bf16x8), 4 loads per thread per t8
//     (was 16): G13, scalar bf16 loads are the measured 2-2.5x trap.
//   - transposed LDS writes paired: rows 2r,2r+1 adjacent in pkT/vT second
//     index -> one 4B store (16 stores vs 32 scalar 2B).
//   - ksum in 8 register accumulators, one-time LDS atomicAdd after pass 1.
//   LDS layout + MFMA + pass-2 byte-identical.
// gemm128 SCHED split unchanged: SCHED=0 (16KB, TLP) for QKV/FFN-up;
// SCHED=1 (R20 dbuf 2-phase) for grid-starved embed/O-proj/FFN-down.

__device__ __forceinline__ void cp16(const bf16* g, bf16* l)
{
    __builtin_amdgcn_global_load_lds(
        (const __attribute__((address_space(1))) void*)g,
        (__attribute__((address_space(3))) void*)l,
        16, 0, 0);
}

__global__ __launch_bounds__(256) void cvt_bf16(
    const float* __restrict__ src, bf16* __restrict__ dst, int n)
{
    for (int i = blockIdx.x * 256 + threadIdx.x; i < n; i += gridDim.x * 256)
        dst[i] = (bf16)src[i];
}

__global__ __launch_bounds__(256) void transpose_f32(
    const float* __restrict__ W, bf16* __restrict__ WT, int K, int N, long elemOff)
{
    __shared__ bf16 tile[32][33];
    const int bn = blockIdx.x * 32;
    const int bk = blockIdx.y * 32;
    const int tx = threadIdx.x & 31, ty = threadIdx.x >> 5;
    for (int r = 0; r < 32; r += 8)
        tile[ty + r][tx] = (bf16)W[elemOff + (long)(bk + ty + r) * N + (bn + tx)];
    __syncthreads();
    for (int r = 0; r < 32; r += 8)
        WT[(long)(bn + ty + r) * K + (bk + tx)] = tile[tx][ty + r];
}

// z=0..3 -> transpose 512x512 slice of {Wq,Wk,Wv,Wo}[layer] into
// {WqkvT+0, WqkvT+256K, WqkvT+512K, WoT}.
__global__ __launch_bounds__(256) void prep_qkvo(
    const float* __restrict__ Wq, const float* __restrict__ Wk,
    const float* __restrict__ Wv, const float* __restrict__ Wo,
    bf16* __restrict__ WqkvT, bf16* __restrict__ WoT, long elemOff)
{
    __shared__ bf16 tile[32][33];
    const int z = blockIdx.z;
    const float* W = (z == 0) ? Wq : (z == 1) ? Wk : (z == 2) ? Wv : Wo;
    bf16* WT = (z < 3) ? (WqkvT + (long)z * 262144) : WoT;
    const int bn = blockIdx.x * 32;
    const int bk = blockIdx.y * 32;
    const int tx = threadIdx.x & 31, ty = threadIdx.x >> 5;
    for (int r = 0; r < 32; r += 8)
        tile[ty + r][tx] = (bf16)W[elemOff + (long)(bk + ty + r) * 512 + (bn + tx)];
    __syncthreads();
    for (int r = 0; r < 32; r += 8)
        WT[(long)(bn + ty + r) * 512 + (bk + tx)] = tile[tx][ty + r];
}

// z=0: W1 [512][2048] -> W1T [2048][512];  z=1: W2 [2048][512] -> W2T [512][2048]
__global__ __launch_bounds__(256) void prep_ffn(
    const float* __restrict__ W1, const float* __restrict__ W2,
    bf16* __restrict__ W1T, bf16* __restrict__ W2T, long elemOff)
{
    __shared__ bf16 tile[32][33];
    const int z = blockIdx.z;
    const float* W = z ? W2 : W1;
    bf16* WT = z ? W2T : W1T;
    const int N = z ? 512 : 2048;
    const int K = z ? 2048 : 512;
    const int bn = (z ? blockIdx.y : blockIdx.x) * 32;
    const int bk = (z ? blockIdx.x : blockIdx.y) * 32;
    const int tx = threadIdx.x & 31, ty = threadIdx.x >> 5;
    for (int r = 0; r < 32; r += 8)
        tile[ty + r][tx] = (bf16)W[elemOff + (long)(bk + ty + r) * N + (bn + tx)];
    __syncthreads();
    for (int r = 0; r < 32; r += 8)
        WT[(long)(bn + ty + r) * K + (bk + tx)] = tile[tx][ty + r];
}

// all 4 layers' {bq,bk,bv} -> bqkv_all[l][1536] in one launch (24 blocks)
__global__ __launch_bounds__(256) void concat_all(
    const float* __restrict__ bq, const float* __restrict__ bk,
    const float* __restrict__ bv, float* __restrict__ dst)
{
    const int i = blockIdx.x * 256 + threadIdx.x;   // 0..6143
    if (i >= 6144) return;
    const int lay = i / 1536;
    const int rem = i - lay * 1536;
    float v;
    if (rem < 512)        v = bq[lay * 512 + rem];
    else if (rem < 1024)  v = bk[lay * 512 + rem - 512];
    else                  v = bv[lay * 512 + rem - 1024];
    dst[lay * 1536 + rem] = v;
}

__global__ __launch_bounds__(256) void build_x0(
    const float* __restrict__ hs, const int* __restrict__ resets,
    bf16* __restrict__ xb)
{
    const int b = blockIdx.x;
    const bool rz = (resets[b] != 0);
    const long base = (long)b * 513 * 512;
    for (int d = threadIdx.x; d < 512; d += 256)
        xb[base + d] = rz ? (bf16)0.f : (bf16)hs[b * 512 + d];
}

// GEMM: C[M,N] = A[M,K] @ BT[N,K]^T + bias(fp32).  128x128 tile, BK=32,
// 4 waves x (4x4) 16x16x32 MFMA, global_load_lds(16B) direct-to-LDS staging.
// LDS [128][32] linear dest; T2 XOR swizzle via pre-swizzled GLOBAL source
// (ksw) + swizzled read seg (qx).  N%128==0; M tail via overlap clamp.
// A row stride lda, C row stride ldc.  Bijective XCD swizzle.
// ROWMAP==1: row += row/512 + 1.  ACT: 0=none 1=relu 2=relu+eps 3=relu+eps iff col<1024.
// SCHED: 0 = single-buffer 2-barrier (R23); 1 = dbuf single-barrier 2-phase (R20).
template<int ROWMAP, int ACT, int SCHED>
__global__ __launch_bounds__(256) void gemm128(
    const bf16* __restrict__ A, const bf16* __restrict__ BT,
    const float* __restrict__ bias, bf16* __restrict__ outB,
    int M, int N, int K, int lda, int ldc)
{
    __shared__ bf16 As[(SCHED + 1) * 128 * 32];
    __shared__ bf16 Bs[(SCHED + 1) * 128 * 32];
    const int tid  = threadIdx.x;
    const int wave = tid >> 6;
    const int lane = tid & 63;
    const int q    = lane >> 4;
    const int lm   = lane & 15;
    const int wr   = wave >> 1, wc = wave & 1;

    // bijective XCD swizzle (m204): orig%8 = XCD slot -> contiguous partition
    int flat;
    {
        const int nwg  = gridDim.x * gridDim.y;
        const int orig = blockIdx.y * gridDim.x + blockIdx.x;
        const int qq = nwg >> 3, rr = nwg & 7;
        const int xcd = orig & 7, idx = orig >> 3;
        flat = (xcd < rr ? xcd * (qq + 1) : rr * (qq + 1) + (xcd - rr) * qq) + idx;
    }
    const int bx = flat % gridDim.x;
    const int by = flat / gridDim.x;
    int m0 = by * 128;
    if (m0 > M - 128) m0 = M - 128;            // tail overlap clamp
    const int n0 = bx * 128;

    // staging geometry: wave w issue i deposits rows w*32+i*16+(l>>2) at
    // linear LDS slot l (elem row*32 + (l&3)*8).  T2: lane fetches k-seg
    // (l&3)^((l>>2)&3) so physical (row,kp) holds logical kp^(row&3).
    const int r0  = wave * 32 + (lane >> 2);
    const int ksw = ((lane & 3) ^ ((lane >> 2) & 3)) * 8;
    const bf16* Ag0 = A  + (long)(m0 + r0) * lda + ksw;
    const bf16* Ag1 = A  + (long)(m0 + r0 + 16) * lda + ksw;
    const bf16* Bg0 = BT + (long)(n0 + r0) * K + ksw;
    const bf16* Bg1 = BT + (long)(n0 + r0 + 16) * K + ksw;

    // read-side swizzle: logical seg q lives at physical q^(row&3), row&3 = lm&3
    const int qx = (q ^ (lm & 3)) * 8;

    f32x4 acc[4][4];
    for (int i = 0; i < 4; i++) for (int j = 0; j < 4; j++)
        for (int r = 0; r < 4; r++) acc[i][j][r] = 0.f;

    if constexpr (SCHED == 0) {
        bf16* Al0 = As + wave * 1024;
        bf16* Al1 = As + wave * 1024 + 512;
        bf16* Bl0 = Bs + wave * 1024;
        bf16* Bl1 = Bs + wave * 1024 + 512;
        for (int k0 = 0; k0 < K; k0 += 32) {
            cp16(Ag0 + k0, Al0);
            cp16(Ag1 + k0, Al1);
            cp16(Bg0 + k0, Bl0);
            cp16(Bg1 + k0, Bl1);
            __syncthreads();                   // drains vmcnt -> DMA landed
            bf16x8 af[4], bfr[4];
            #pragma unroll
            for (int i = 0; i < 4; i++)
                af[i] = *(const bf16x8*)(As + (wr * 64 + i * 16 + lm) * 32 + qx);
            #pragma unroll
            for (int j = 0; j < 4; j++)
                bfr[j] = *(const bf16x8*)(Bs + (wc * 64 + j * 16 + lm) * 32 + qx);
            #pragma unroll
            for (int i = 0; i < 4; i++)
                #pragma unroll
                for (int j = 0; j < 4; j++)
                    acc[i][j] = __builtin_amdgcn_mfma_f32_16x16x32_bf16(
                        af[i], bfr[j], acc[i][j], 0, 0, 0);
            __syncthreads();                   // LDS safe for next DMA
        }
    } else {
        // R20 2-phase: STAGE(t+1) first, compute buf[cur], one barrier/iter.
        const int lb = wave * 1024;
        const int NT = K >> 5;
#define STAGE24(kt, buf)                                       \
        do {                                                   \
            const int _k0 = (kt) * 32;                         \
            cp16(Ag0 + _k0, &As[(buf) * 4096 + lb]);           \
            cp16(Ag1 + _k0, &As[(buf) * 4096 + lb + 512]);     \
            cp16(Bg0 + _k0, &Bs[(buf) * 4096 + lb]);           \
            cp16(Bg1 + _k0, &Bs[(buf) * 4096 + lb + 512]);     \
        } while (0)
        STAGE24(0, 0);
        asm volatile("s_waitcnt vmcnt(0)" ::: "memory");
        __builtin_amdgcn_s_barrier();
        int cur = 0;
        for (int t = 0; t < NT; ++t) {
            if (t + 1 < NT) STAGE24(t + 1, cur ^ 1);   // next-tile DMA FIRST
            bf16x8 af[4], bfr[4];
            #pragma unroll
            for (int i = 0; i < 4; i++)
                af[i] = *(const bf16x8*)(&As[cur * 4096 + (wr * 64 + i * 16 + lm) * 32 + qx]);
            #pragma unroll
            for (int j = 0; j < 4; j++)
                bfr[j] = *(const bf16x8*)(&Bs[cur * 4096 + (wc * 64 + j * 16 + lm) * 32 + qx]);
            #pragma unroll
            for (int i = 0; i < 4; i++)
                #pragma unroll
                for (int j = 0; j < 4; j++)
                    acc[i][j] = __builtin_amdgcn_mfma_f32_16x16x32_bf16(
                        af[i], bfr[j], acc[i][j], 0, 0, 0);
            asm volatile("s_waitcnt vmcnt(0)" ::: "memory");
            __builtin_amdgcn_s_barrier();
            cur ^= 1;
        }
#undef STAGE24
    }

    // C/D: col = lane&15, row = (lane>>4)*4 + r  [session-verified]
    #pragma unroll
    for (int j = 0; j < 4; j++) {
        const int col = n0 + wc * 64 + j * 16 + lm;
        const float bv = bias[col];
        #pragma unroll
        for (int i = 0; i < 4; i++) {
            #pragma unroll
            for (int r = 0; r < 4; r++) {
                int row = m0 + wr * 64 + i * 16 + q * 4 + r;
                float vv = acc[i][j][r] + bv;
                if (ACT == 1) vv = fmaxf(vv, 0.f);
                if (ACT == 2) vv = fmaxf(vv, 0.f) + 1e-3f;
                if (ACT == 3 && col < 1024) vv = fmaxf(vv, 0.f) + 1e-3f;
                if (ROWMAP == 1) row = row + (row >> 9) + 1;
                outB[(long)row * ldc + col] = (bf16)vv;
            }
        }
    }
}

// FAVOR+ attention, full MFMA.  Reads pq/pk/vv as column slices {0,512,1024}
// of the strided qkv[row][1536] buffer; writes ao back into the pq slice
// (per-(b,h) alias safe: each t8 tile's pq rows are staged before overwrite).
// R25: pass-1 staging vectorized (16B loads, paired 4B transposed writes,
// register ksum + one-time LDS atomicAdd).  LDS layout/MFMA unchanged.
#define FP 72
__global__ __launch_bounds__(256) void favor_mfma(bf16* qkv)
{
    const int bh = blockIdx.x;
    const int b = bh >> 3, h = bh & 7;
    const long rbQ = (long)b * 513 * 1536 + h * 64;
    const long rbK = rbQ + 512;
    const long rbV = rbQ + 1024;

    __shared__ bf16 pkT[64][FP];
    __shared__ bf16 vT [64][FP];
    __shared__ bf16 kvT[64][FP];
    __shared__ bf16 pqS[64][FP];
    __shared__ float ksumS[64];
    __shared__ float denS[64];

    const int tid  = threadIdx.x;
    const int wave = tid >> 6;
    const int lane = tid & 63;
    const int q    = lane >> 4;
    const int lm   = lane & 15;
    const int wr   = wave >> 1, wc = wave & 1;

    if (tid < 64) ksumS[tid] = 0.f;

    // pass-1 staging map: thread -> rows {2*r2, 2*r2+1}, d-seg dseg..dseg+7
    const int r2   = tid >> 3;          // 0..31
    const int dseg = (tid & 7) * 8;     // 0..56
    const int ra   = 2 * r2;

    float ks8[8];
    #pragma unroll
    for (int e = 0; e < 8; e++) ks8[e] = 0.f;

    f32x4 akv[2][2];
    for (int i = 0; i < 2; i++) for (int j = 0; j < 2; j++)
        for (int r = 0; r < 4; r++) akv[i][j][r] = 0.f;

    for (int t8 = 0; t8 < 9; t8++) {
        const int s0 = t8 * 64;
        const int ga = s0 + ra;
        const int gb = ga + 1;
        bf16x8 pka, pkb, va, vb;
        if (ga < 513) {
            pka = *(const bf16x8*)(qkv + rbK + (long)ga * 1536 + dseg);
            va  = *(const bf16x8*)(qkv + rbV + (long)ga * 1536 + dseg);
        } else {
            #pragma unroll
            for (int e = 0; e < 8; e++) { pka[e] = (bf16)0.f; va[e] = (bf16)0.f; }
        }
        if (gb < 513) {
            pkb = *(const bf16x8*)(qkv + rbK + (long)gb * 1536 + dseg);
            vb  = *(const bf16x8*)(qkv + rbV + (long)gb * 1536 + dseg);
        } else {
            #pragma unroll
            for (int e = 0; e < 8; e++) { pkb[e] = (bf16)0.f; vb[e] = (bf16)0.f; }
        }
        #pragma unroll
        for (int e = 0; e < 8; e++) {
            union { unsigned u; bf16 h[2]; } pw, vw2;
            pw.h[0]  = pka[e]; pw.h[1]  = pkb[e];
            vw2.h[0] = va[e];  vw2.h[1] = vb[e];
            *(unsigned*)&pkT[dseg + e][ra] = pw.u;    // 4B aligned: 144k+4*r2
            *(unsigned*)&vT [dseg + e][ra] = vw2.u;
            ks8[e] += (float)pka[e] + (float)pkb[e];
        }
        __syncthreads();
        #pragma unroll
        for (int ks = 0; ks < 2; ks++) {
            bf16x8 a0 = *(const bf16x8*)(&pkT[wr * 32 + lm     ][ks * 32 + q * 8]);
            bf16x8 a1 = *(const bf16x8*)(&pkT[wr * 32 + 16 + lm][ks * 32 + q * 8]);
            bf16x8 b0 = *(const bf16x8*)(&vT [wc * 32 + lm     ][ks * 32 + q * 8]);
            bf16x8 b1 = *(const bf16x8*)(&vT [wc * 32 + 16 + lm][ks * 32 + q * 8]);
            akv[0][0] = __builtin_amdgcn_mfma_f32_16x16x32_bf16(a0, b0, akv[0][0], 0, 0, 0);
            akv[0][1] = __builtin_amdgcn_mfma_f32_16x16x32_bf16(a0, b1, akv[0][1], 0, 0, 0);
            akv[1][0] = __builtin_amdgcn_mfma_f32_16x16x32_bf16(a1, b0, akv[1][0], 0, 0, 0);
            akv[1][1] = __builtin_amdgcn_mfma_f32_16x16x32_bf16(a1, b1, akv[1][1], 0, 0, 0);
        }
        __syncthreads();
    }
    #pragma unroll
    for (int e = 0; e < 8; e++)
        atomicAdd(&ksumS[dseg + e], ks8[e]);
    #pragma unroll
    for (int i = 0; i < 2; i++)
        #pragma unroll
        for (int j = 0; j < 2; j++)
            #pragma unroll
            for (int r = 0; r < 4; r++)
                kvT[wc * 32 + j * 16 + lm][wr * 32 + i * 16 + q * 4 + r] =
                    (bf16)akv[i][j][r];
    __syncthreads();

    const int prow = tid >> 2;
    const int pseg = (tid & 3) * 16;
    for (int t8 = 0; t8 < 9; t8++) {
        const int s0 = t8 * 64;
        const int gs = s0 + prow;
        if (gs < 513) {
            *(bf16x8*)(&pqS[prow][pseg])     = *(const bf16x8*)(qkv + rbQ + (long)gs * 1536 + pseg);
            *(bf16x8*)(&pqS[prow][pseg + 8]) = *(const bf16x8*)(qkv + rbQ + (long)gs * 1536 + pseg + 8);
        } else {
            bf16x8 z;
            for (int r = 0; r < 8; r++) z[r] = (bf16)0.f;
            *(bf16x8*)(&pqS[prow][pseg])     = z;
            *(bf16x8*)(&pqS[prow][pseg + 8]) = z;
        }
        __syncthreads();
        {
            const int s = tid >> 2, mb = (tid & 3) * 16;
            float dp = 0.f;
            #pragma unroll
            for (int m2 = 0; m2 < 16; m2++)
                dp += (float)pqS[s][mb + m2] * ksumS[mb + m2];
            dp += __shfl_xor(dp, 1);
            dp += __shfl_xor(dp, 2);
            if ((tid & 3) == 0) denS[s] = dp;
        }
        __syncthreads();
        f32x4 an[4];
        for (int j = 0; j < 4; j++)
            for (int r = 0; r < 4; r++) an[j][r] = 0.f;
        #pragma unroll
        for (int ks = 0; ks < 2; ks++) {
            bf16x8 a = *(const bf16x8*)(&pqS[wave * 16 + lm][ks * 32 + q * 8]);
            #pragma unroll
            for (int j = 0; j < 4; j++) {
                bf16x8 bb = *(const bf16x8*)(&kvT[j * 16 + lm][ks * 32 + q * 8]);
                an[j] = __builtin_amdgcn_mfma_f32_16x16x32_bf16(a, bb, an[j], 0, 0, 0);
            }
        }
        #pragma unroll
        for (int j = 0; j < 4; j++) {
            #pragma unroll
            for (int r = 0; r < 4; r++) {
                const int sl  = wave * 16 + q * 4 + r;
                const int gs2 = s0 + sl;
                if (gs2 < 513) {
                    const int d = j * 16 + lm;
                    qkv[rbQ + (long)gs2 * 1536 + d] = (bf16)(an[j][r] / denS[sl]);
                }
            }
        }
        __syncthreads();
    }
}

__global__ __launch_bounds__(256) void ln_res(
    const bf16* __restrict__ y, int ldy, const float* __restrict__ sc,
    const float* __restrict__ bi, bf16* __restrict__ xb)
{
    const int row  = blockIdx.x * 4 + (threadIdx.x >> 6);
    const int lane = threadIdx.x & 63;
    const bf16* yr = y  + (long)row * ldy + lane * 8;
    bf16*       xr = xb + (long)row * 512 + lane * 8;
    bf16x8 yv = *(const bf16x8*)yr;
    bf16x8 xv = *(const bf16x8*)xr;
    float v[8];
    float sum = 0.f;
    #pragma unroll
    for (int i = 0; i < 8; i++) { v[i] = (float)yv[i] + (float)xv[i]; sum += v[i]; }
    #pragma unroll
    for (int o = 32; o; o >>= 1) sum += __shfl_xor(sum, o);
    const float mean = sum * (1.f / 512.f);
    float vs = 0.f;
    #pragma unroll
    for (int i = 0; i < 8; i++) { float dd = v[i] - mean; vs += dd * dd; }
    #pragma unroll
    for (int o = 32; o; o >>= 1) vs += __shfl_xor(vs, o);
    const float rstd = rsqrtf(vs * (1.f / 512.f) + 1e-6f);
    bf16x8 ov;
    #pragma unroll
    for (int i = 0; i < 8; i++)
        ov[i] = (bf16)((v[i] - mean) * rstd * sc[lane * 8 + i] + bi[lane * 8 + i]);
    *(bf16x8*)xr = ov;
}

__global__ __launch_bounds__(256) void final_head(
    const bf16* __restrict__ xb, const float* __restrict__ Wqp,
    const float* __restrict__ bqp, float* __restrict__ out)
{
    const int b = blockIdx.x;
    const bf16* xr = xb + (long)b * 513 * 512;
    for (int i = threadIdx.x; i < 512; i += 256) out[b * 512 + i] = (float)xr[i];
    const int a = threadIdx.x & 15, g = threadIdx.x >> 4;
    float p = 0.f;
    for (int k = g * 32; k < g * 32 + 32; k++)
        p += (float)xr[k] * Wqp[k * 16 + a];
    __shared__ float red[256];
    red[threadIdx.x] = p;
    __syncthreads();
    if (threadIdx.x < 16) {
        float s = bqp[a];
        for (int g2 = 0; g2 < 16; g2++) s += red[g2 * 16 + a];
        out[64 * 512 + b * 16 + a] = s;
    }
}

extern "C" void kernel_launch(void* const* d_in, const int* in_sizes, int n_in,
                              void* d_out, int out_size, void* d_ws, size_t ws_size,
                              hipStream_t stream)
{
    (void)in_sizes; (void)n_in; (void)out_size; (void)ws_size;
    const float* hs    = (const float*)d_in[0];
    const float* ins   = (const float*)d_in[1];
    const int*   resets= (const int*)d_in[2];
    const float* W_emb = (const float*)d_in[3];
    const float* b_emb = (const float*)d_in[4];
    const float* Wq    = (const float*)d_in[5];
    const float* bq    = (const float*)d_in[6];
    const float* Wk    = (const float*)d_in[7];
    const float* bk    = (const float*)d_in[8];
    const float* Wv    = (const float*)d_in[9];
    const float* bv    = (const float*)d_in[10];
    const float* Wo    = (const float*)d_in[11];
    const float* bo    = (const float*)d_in[12];
    const float* ln1s  = (const float*)d_in[13];
    const float* ln1b  = (const float*)d_in[14];
    const float* ln2s  = (const float*)d_in[15];
    const float* ln2b  = (const float*)d_in[16];
    const float* W1    = (const float*)d_in[17];
    const float* b1    = (const float*)d_in[18];
    const float* W2    = (const float*)d_in[19];
    const float* b2    = (const float*)d_in[20];
    const float* Wqp   = (const float*)d_in[21];
    const float* bqp   = (const float*)d_in[22];
    float* out = (float*)d_out;
    char* ws  = (char*)d_ws;

    // ---- workspace layout (bytes), peak ~149.30 MB ----
    // xb   [32832][512]  bf16   @ 0            (33,619,968)
    // qkv  [32832][1536] bf16   @ 33,619,968   (100,859,904)
    //   f  [16416][2048] bf16   @ qkv+0        (67,239,936)   (FFN, qkv dead)
    //   y2 [32832][512]  bf16   @ qkv+67,239,936 (33,619,968) (exact fit)
    // WembT               @ 134,479,872  (131,072)  -> reused as bqkv_all after embed
    // LW                  @ 134,610,944: WqkvT(1,572,864) WoT(524,288)
    //                       W1T(2,097,152) W2T(2,097,152)
    // insb                @ 140,908,544  (8,388,608)  -> end 149,297,152
    bf16* xb   = (bf16*)(ws);
    bf16* qkv  = (bf16*)(ws + 33619968);
    bf16* f    = qkv;
    bf16* y2   = (bf16*)(ws + 33619968 + 67239936);
    bf16* WembT= (bf16*)(ws + 134479872);
    float* bqkv_all = (float*)(ws + 134479872);   // 24KB, reuses WembT after embed
    char* LW   = ws + 134610944;
    bf16* WqkvT= (bf16*)(LW + 0);
    bf16* WoT  = (bf16*)(LW + 1572864);
    bf16* W1T  = (bf16*)(LW + 2097152);
    bf16* W2T  = (bf16*)(LW + 4194304);
    bf16* insb = (bf16*)(ws + 140908544);

    cvt_bf16<<<4096, 256, 0, stream>>>(ins, insb, 4194304);
    transpose_f32<<<dim3(16, 4), 256, 0, stream>>>(W_emb, WembT, 128, 512, 0);
    build_x0<<<64, 256, 0, stream>>>(hs, resets, xb);
    gemm128<1, 0, 1><<<dim3(4, 256), 256, 0, stream>>>(
        insb, WembT, b_emb, xb, 32768, 512, 128, 128, 512);
    // WembT dead from here; bqkv_all takes the region
    concat_all<<<24, 256, 0, stream>>>(bq, bk, bv, bqkv_all);

    for (int l = 0; l < 4; l++) {
        const long o512  = (long)l * 262144;
        const long o2048 = (long)l * 1048576;
        prep_qkvo<<<dim3(16, 16, 4), 256, 0, stream>>>(Wq, Wk, Wv, Wo, WqkvT, WoT, o512);
        prep_ffn<<<dim3(64, 16, 2), 256, 0, stream>>>(W1, W2, W1T, W2T, o2048);

        // fused QKV (demand 12 blocks/CU -> SCHED=0 keeps TLP)
        gemm128<0, 3, 0><<<dim3(12, 257), 256, 0, stream>>>(
            xb, WqkvT, bqkv_all + l * 1536, qkv, 32832, 1536, 512, 512, 1536);
        favor_mfma<<<512, 256, 0, stream>>>(qkv);
        // O-proj (demand 4/CU <= 5-block cap -> SCHED=1 pipeline, free)
        gemm128<0, 0, 1><<<dim3(4, 257), 256, 0, stream>>>(
            qkv, WoT, bo + l * 512, qkv + 512, 32832, 512, 512, 1536, 1536);
        ln_res<<<8208, 256, 0, stream>>>(qkv + 512, 1536, ln1s + l * 512, ln1b + l * 512, xb);

        // FFN in two 16416-row chunks; f + y2 alias exactly inside qkv region
        for (int c = 0; c < 2; c++) {
            const long r0 = (long)c * 16416;
            // up: demand 8/CU -> SCHED=0
            gemm128<0, 1, 0><<<dim3(16, 129), 256, 0, stream>>>(
                xb + r0 * 512, W1T, b1 + l * 2048, f, 16416, 2048, 512, 512, 2048);
            // down: demand 2/CU, K=2048 (64 iters) -> SCHED=1 pipeline
            gemm128<0, 0, 1><<<dim3(4, 129), 256, 0, stream>>>(
                f, W2T, b2 + l * 512, y2 + r0 * 512, 16416, 512, 2048, 2048, 512);
        }
        ln_res<<<8208, 256, 0, stream>>>(y2, 512, ln2s + l * 512, ln2b + l * 512, xb);
    }

    final_head<<<64, 256, 0, stream>>>(xb, Wqp, bqp, out);
}